// Round 12
// baseline (680.190 us; speedup 1.0000x reference)
//
#include <hip/hip_runtime.h>

// ---------------- problem constants ----------------
#define BB 8
#define CC 256
#define TT 256
#define FF 128
#define DD 64
#define HH 128
#define NHEADS 4
#define KK 8
#define II 512            // D*K
#define T2 128
#define F2 64
#define T4 64
#define F4 32
#define P4 2048           // T4*F4

// freq pathway: N=512 seqs, L=25 ; time pathway: N=256 seqs, L=57
#define LF 25
#define LT 57
#define MF (512*LF)       // 12800 (= 100*128)
#define MT (256*LT)       // 14592 (= 114*128)

typedef __attribute__((ext_vector_type(8))) short bf16x8;
typedef __attribute__((ext_vector_type(4))) float f32x4;

__device__ __forceinline__ ushort f2b(float x) {
    unsigned u = __float_as_uint(x);
    unsigned r = (u + 0x7FFFu + ((u >> 16) & 1u)) >> 16;
    return (ushort)r;
}
__device__ __forceinline__ float b2f(ushort x) {
    return __uint_as_float(((unsigned)x) << 16);
}
__device__ __forceinline__ unsigned cvtpk_bf16(float lo, float hi) {
    unsigned r;
    asm("v_cvt_pk_bf16_f32 %0, %1, %2" : "=v"(r) : "v"(lo), "v"(hi));
    return r;
}

// ---------------- ONE mega weight-pack kernel ----------------
__global__ __launch_bounds__(256) void pack_all_k(
    const float* __restrict__ cw, const float* __restrict__ fw,
    const float* __restrict__ upw0, const float* __restrict__ upw1,
    const float* __restrict__ qkv_w, const float* __restrict__ ow,
    const float* __restrict__ dw0, const float* __restrict__ dw1,
    const float* __restrict__ f_pw, const float* __restrict__ t_pw,
    const float* __restrict__ f_ctw, const float* __restrict__ t_ctw,
    const float* __restrict__ f_Wx, const float* __restrict__ f_Whw,
    const float* __restrict__ t_Wx, const float* __restrict__ t_Whw,
    ushort* __restrict__ cw16, ushort* __restrict__ fw16,
    ushort* __restrict__ WupT0, ushort* __restrict__ WupT1,
    ushort* __restrict__ qkvwT, ushort* __restrict__ owT,
    ushort* __restrict__ WT9d0, ushort* __restrict__ WT9d1,
    ushort* __restrict__ pwF16, ushort* __restrict__ pwT16,
    ushort* __restrict__ WctF, ushort* __restrict__ WctT_,
    ushort* __restrict__ WcatF, ushort* __restrict__ WcatTm)
{
    int bid = blockIdx.x, tid = threadIdx.x;
    if (bid < 64)        { int g = bid * 256 + tid; cw16[g] = f2b(cw[g]); return; }
    if (bid < 128)       { int g = (bid - 64) * 256 + tid; fw16[g] = f2b(fw[g]); return; }
    if (bid < 256) {     // upw0 / upw1
        const float* w = (bid < 192) ? upw0 : upw1;
        ushort* O = (bid < 192) ? WupT0 : WupT1;
        int g = ((bid - 128) & 63) * 256 + tid;
        int c = g & 63; int n = g >> 6;
        int parity = n >> 6, d = n & 63;
        O[g] = f2b(w[((d * 64 + c) * 2 + (1 - (parity >> 1))) * 2 + (1 - (parity & 1))]);
        return;
    }
    if (bid < 304) {     // qkv_w^T: K=64, N=192
        int g = (bid - 256) * 256 + tid;
        int k = g & 63, n = g >> 6;
        qkvwT[g] = f2b(qkv_w[k * 192 + n]); return;
    }
    if (bid < 320) {     // ow^T: 64x64
        int g = (bid - 304) * 256 + tid;
        int k = g & 63, n = g >> 6;
        owT[g] = f2b(ow[k * 64 + n]); return;
    }
    if (bid < 608) {     // dw9 x2
        const float* w = (bid < 464) ? dw0 : dw1;
        ushort* O = (bid < 464) ? WT9d0 : WT9d1;
        int g = ((bid - 320) % 144) * 256 + tid;
        int c = g & 63; int rest = g >> 6;
        int d = rest & 63; int tap = rest >> 6;
        O[g] = f2b(w[(d * 64 + c) * 9 + tap]); return;
    }
    if (bid < 1632) {    // pw x2 (131072 each)
        const float* w = (bid < 1120) ? f_pw : t_pw;
        ushort* O = (bid < 1120) ? pwF16 : pwT16;
        int g = ((bid - 608) % 512) * 256 + tid;
        O[g] = f2b(w[g]); return;
    }
    if (bid < 3680) {    // wct2T x2 (262144 each)
        const float* ctw = (bid < 2656) ? f_ctw : t_ctw;
        ushort* O = (bid < 2656) ? WctF : WctT_;
        int g = ((bid - 1632) % 1024) * 256 + tid;
        int k = g & 511; int n = g >> 9;
        int tap = n >> 6, d = n & 63;
        O[g] = f2b(ctw[((d * 512) + k) * 8 + tap]); return;
    }
    {                    // wcatT x2 (524288 each)
        const float* Wx  = (bid < 5728) ? f_Wx  : t_Wx;
        const float* Whw = (bid < 5728) ? f_Whw : t_Whw;
        ushort* O = (bid < 5728) ? WcatF : WcatTm;
        int g = ((bid - 3680) % 2048) * 256 + tid;
        int k = g & 511; int n = g >> 9;
        int dir = n >> 9; int c = n & 511;
        float v = (c < 384) ? Wx[(dir * 512 + k) * 384 + c]
                            : Whw[(dir * 512 + k) * 128 + (c - 384)];
        O[g] = f2b(v);
    }
}

// ---------------- W3 = pw @ W2 for BOTH pathways ----------------
__global__ __launch_bounds__(256) void w3_gemm_k(
    const ushort* __restrict__ pwA, const ushort* __restrict__ wctA,
    const ushort* __restrict__ pwB, const ushort* __restrict__ wctB,
    ushort* __restrict__ w3A, ushort* __restrict__ w3B)
{
    const int M = 256, K = 512;
    const ushort* A16  = blockIdx.z ? pwB  : pwA;
    const ushort* BT16 = blockIdx.z ? wctB : wctA;
    ushort* C16        = blockIdx.z ? w3B  : w3A;
    __shared__ ushort As[128][40];
    __shared__ ushort Bs[128][40];
    int m0 = blockIdx.y * 128, n0 = blockIdx.x * 128;
    int tid = threadIdx.x;
    int wave = tid >> 6, lane = tid & 63;
    int wm = (wave & 1) * 64, wn = (wave >> 1) * 64;
    int l15 = lane & 15, lhi = lane >> 4;
    f32x4 acc[4][4] = {};
    int rs = tid >> 2, qs = tid & 3;

    for (int k0 = 0; k0 < K; k0 += 32) {
        *(uint4*)&As[rs][qs * 8]      = *(const uint4*)(A16 + (long long)(m0 + rs) * K + k0 + qs * 8);
        *(uint4*)&As[rs + 64][qs * 8] = *(const uint4*)(A16 + (long long)(m0 + rs + 64) * K + k0 + qs * 8);
        *(uint4*)&Bs[rs][qs * 8]      = *(const uint4*)(BT16 + (long long)(n0 + rs) * K + k0 + qs * 8);
        *(uint4*)&Bs[rs + 64][qs * 8] = *(const uint4*)(BT16 + (long long)(n0 + rs + 64) * K + k0 + qs * 8);
        __syncthreads();
        bf16x8 af[4], bfr[4];
#pragma unroll
        for (int fr = 0; fr < 4; ++fr)
            af[fr] = *(const bf16x8*)&As[wm + fr * 16 + l15][lhi * 8];
#pragma unroll
        for (int fc = 0; fc < 4; ++fc)
            bfr[fc] = *(const bf16x8*)&Bs[wn + fc * 16 + l15][lhi * 8];
#pragma unroll
        for (int fr = 0; fr < 4; ++fr)
#pragma unroll
            for (int fc = 0; fc < 4; ++fc)
                acc[fr][fc] = __builtin_amdgcn_mfma_f32_16x16x32_bf16(af[fr], bfr[fc], acc[fr][fc], 0, 0, 0);
        __syncthreads();
    }
#pragma unroll
    for (int fr = 0; fr < 4; ++fr)
#pragma unroll
        for (int fc = 0; fc < 4; ++fc) {
            int col = n0 + wn + fc * 16 + l15;
#pragma unroll
            for (int r = 0; r < 4; ++r) {
                int row = m0 + wm + fr * 16 + lhi * 4 + r;
                C16[(long long)col * M + row] = f2b(acc[fr][fc][r]);
            }
        }
}

// bias3[n] = sum_i pb[i] * W2[i][n]
__global__ void bias3_red_k(const float* __restrict__ pbF, const float* __restrict__ ctwF,
                            const float* __restrict__ pbT, const float* __restrict__ ctwT,
                            float* __restrict__ b3F, float* __restrict__ b3T)
{
    int n = blockIdx.x; int path = blockIdx.y;
    const float* pb  = path ? pbT  : pbF;
    const float* ctw = path ? ctwT : ctwF;
    float* b3        = path ? b3T  : b3F;
    int d = n & 63, tap = n >> 6;
    int tid = threadIdx.x;
    float s = 0.f;
    for (int i = tid; i < 512; i += 256)
        s += pb[i] * ctw[(d * 512 + i) * 8 + tap];
    __shared__ float red[256];
    red[tid] = s; __syncthreads();
    for (int st = 128; st > 0; st >>= 1) {
        if (tid < st) red[tid] += red[tid + st];
        __syncthreads();
    }
    if (tid == 0) b3[n] = red[0];
}

// ---------------- unfold BOTH pathways in one launch -> bf16 ----------------
__global__ void unfold_both_k(const float* __restrict__ ag,
                              ushort* __restrict__ uF, ushort* __restrict__ uT)
{
    long long gid = (long long)blockIdx.x * blockDim.x + threadIdx.x;
    if (gid < (long long)MF * II) {
        int ch = (int)(gid & 511); int row = (int)(gid >> 9);
        int b = row / (T4 * LF); int rem = row - b * (T4 * LF);
        int t = rem / LF; int l = rem - t * LF;
        int d = ch >> 3, i = ch & 7;
        uF[gid] = f2b(ag[((long long)((b * DD + d) * T4 + t)) * F4 + l + i]);
    } else {
        long long g2 = gid - (long long)MF * II;
        int ch = (int)(g2 & 511); int row = (int)(g2 >> 9);
        int b = row / (F4 * LT); int rem = row - b * (F4 * LT);
        int tt = rem / LT; int l = rem - tt * LT;
        int d = ch >> 3, i = ch & 7;
        uT[g2] = f2b(ag[((long long)((b * DD + d) * T4 + (l + i))) * F4 + tt]);
    }
}

// ---------------- gates GEMM, BOTH pathways; bf16 gate planes ----------------
// grid (8, 100+114); by<100 -> freq, else time.
__global__ __launch_bounds__(256) void gates_fused_k(
    const ushort* __restrict__ uF, const ushort* __restrict__ uT,
    const ushort* __restrict__ WF, const ushort* __restrict__ WTm,
    ushort* __restrict__ GxtF, ushort* __restrict__ GxhF,
    ushort* __restrict__ GfF, ushort* __restrict__ GrF,
    ushort* __restrict__ GxtT, ushort* __restrict__ GxhT,
    ushort* __restrict__ GfT, ushort* __restrict__ GrT,
    const float* __restrict__ f_bf, const float* __restrict__ f_br,
    const float* __restrict__ t_bf, const float* __restrict__ t_br)
{
    __shared__ ushort As[128][40];
    __shared__ ushort Bs[128][40];
    const int K = 512;
    int by = blockIdx.y;
    bool tp = by >= 100;
    const ushort* A16 = tp ? uT : uF;
    const ushort* WT  = tp ? WTm : WF;
    ushort* Gxt = tp ? GxtT : GxtF;
    ushort* Gxh = tp ? GxhT : GxhF;
    ushort* Gf = tp ? GfT : GfF;
    ushort* Gr = tp ? GrT : GrF;
    const float* bfw = tp ? t_bf : f_bf;
    const float* brw = tp ? t_br : f_br;
    int m0 = (tp ? by - 100 : by) * 128;
    int n0 = blockIdx.x * 128;
    int tid = threadIdx.x, wave = tid >> 6, lane = tid & 63;
    int wm = (wave & 1) * 64, wn = (wave >> 1) * 64;
    int l15 = lane & 15, lhi = lane >> 4;
    f32x4 acc[4][4] = {};
    int rs = tid >> 2, qs = tid & 3;

    for (int k0 = 0; k0 < K; k0 += 32) {
        *(uint4*)&As[rs][qs * 8]      = *(const uint4*)(A16 + (long long)(m0 + rs) * K + k0 + qs * 8);
        *(uint4*)&As[rs + 64][qs * 8] = *(const uint4*)(A16 + (long long)(m0 + rs + 64) * K + k0 + qs * 8);
        *(uint4*)&Bs[rs][qs * 8]      = *(const uint4*)(WT + (long long)(n0 + rs) * K + k0 + qs * 8);
        *(uint4*)&Bs[rs + 64][qs * 8] = *(const uint4*)(WT + (long long)(n0 + rs + 64) * K + k0 + qs * 8);
        __syncthreads();
        bf16x8 af[4], bfr[4];
#pragma unroll
        for (int fr = 0; fr < 4; ++fr)
            af[fr] = *(const bf16x8*)&As[wm + fr * 16 + l15][lhi * 8];
#pragma unroll
        for (int fc = 0; fc < 4; ++fc)
            bfr[fc] = *(const bf16x8*)&Bs[wn + fc * 16 + l15][lhi * 8];
#pragma unroll
        for (int fr = 0; fr < 4; ++fr)
#pragma unroll
            for (int fc = 0; fc < 4; ++fc)
                acc[fr][fc] = __builtin_amdgcn_mfma_f32_16x16x32_bf16(af[fr], bfr[fc], acc[fr][fc], 0, 0, 0);
        __syncthreads();
    }
#pragma unroll
    for (int fc = 0; fc < 4; ++fc) {
        int col = n0 + wn + fc * 16 + l15;
        int dir = col >> 9, c = col & 511;
        int cls = c >> 7, h = c & 127;
        int dh = dir * 128 + h;
#pragma unroll
        for (int fr = 0; fr < 4; ++fr) {
#pragma unroll
            for (int r = 0; r < 4; ++r) {
                int row = m0 + wm + fr * 16 + lhi * 4 + r;
                long long idx = (long long)row * 256 + dh;
                float v = acc[fr][fc][r];
                if (cls == 0)      Gxt[idx] = f2b(v);
                else if (cls == 3) Gxh[idx] = f2b(v);
                else if (cls == 1) Gf[idx] = f2b(1.f / (1.f + __expf(-(v + bfw[dh]))));
                else               Gr[idx] = f2b(1.f / (1.f + __expf(-(v + brw[dh]))));
            }
        }
    }
}

// ---------------- SRU scan, BOTH pathways; bf16 gate planes ----------------
__global__ void sru_scan_both_k(
    const ushort* __restrict__ GxtF, const ushort* __restrict__ GxhF,
    const ushort* __restrict__ GfF, const ushort* __restrict__ GrF,
    ushort* __restrict__ hF,
    const ushort* __restrict__ GxtT, const ushort* __restrict__ GxhT,
    const ushort* __restrict__ GfT, const ushort* __restrict__ GrT,
    ushort* __restrict__ hT)
{
    int gid = blockIdx.x * blockDim.x + threadIdx.x;
    const ushort *Gxt, *Gxh, *Gf, *Gr; ushort* hout; int L;
    if (gid < 512 * 256) {
        Gxt = GxtF; Gxh = GxhF; Gf = GfF; Gr = GrF; hout = hF; L = LF;
    } else {
        gid -= 512 * 256;
        Gxt = GxtT; Gxh = GxhT; Gf = GfT; Gr = GrT; hout = hT; L = LT;
    }
    int h = gid & 127; int dir = (gid >> 7) & 1; int n = gid >> 8;
    int dh = dir * 128 + h;
    float c = 0.f;
    for (int s = 0; s < L; ++s) {
        int l = dir ? (L - 1 - s) : s;
        long long off = (long long)(n * L + l) * 256 + dh;
        float xt = b2f(Gxt[off]), xh = b2f(Gxh[off]);
        float f = b2f(Gf[off]);
        float r = b2f(Gr[off]);
        c = f * c + (1.f - f) * xt;
        float hv = r * c + (1.f - r) * xh;
        hout[off] = f2b(hv);
    }
}

// ---------------- composite Y GEMM, BOTH pathways; bf16 Y output ----------------
// grid (4, 100+114)
__global__ __launch_bounds__(256) void gemmW_both_k(
    const ushort* __restrict__ hF, const ushort* __restrict__ W3F,
    ushort* __restrict__ YF, const float* __restrict__ b3F,
    const ushort* __restrict__ hT, const ushort* __restrict__ W3T,
    ushort* __restrict__ YT, const float* __restrict__ b3T)
{
    __shared__ ushort As[128][40];
    __shared__ ushort Bs[128][40];
    const int N = 512, K = 256;
    int by = blockIdx.y;
    bool tp = by >= 100;
    const ushort* A16 = tp ? hT : hF;
    const ushort* WT  = tp ? W3T : W3F;
    ushort* C16       = tp ? YT : YF;
    const float* bias = tp ? b3T : b3F;
    int m0 = (tp ? by - 100 : by) * 128;
    int n0 = blockIdx.x * 128;
    int tid = threadIdx.x, wave = tid >> 6, lane = tid & 63;
    int wm = (wave & 1) * 64, wn = (wave >> 1) * 64;
    int l15 = lane & 15, lhi = lane >> 4;
    f32x4 acc[4][4] = {};
    int rs = tid >> 2, qs = tid & 3;

    for (int k0 = 0; k0 < K; k0 += 32) {
        *(uint4*)&As[rs][qs * 8]      = *(const uint4*)(A16 + (long long)(m0 + rs) * K + k0 + qs * 8);
        *(uint4*)&As[rs + 64][qs * 8] = *(const uint4*)(A16 + (long long)(m0 + rs + 64) * K + k0 + qs * 8);
        *(uint4*)&Bs[rs][qs * 8]      = *(const uint4*)(WT + (long long)(n0 + rs) * K + k0 + qs * 8);
        *(uint4*)&Bs[rs + 64][qs * 8] = *(const uint4*)(WT + (long long)(n0 + rs + 64) * K + k0 + qs * 8);
        __syncthreads();
        bf16x8 af[4], bfr[4];
#pragma unroll
        for (int fr = 0; fr < 4; ++fr)
            af[fr] = *(const bf16x8*)&As[wm + fr * 16 + l15][lhi * 8];
#pragma unroll
        for (int fc = 0; fc < 4; ++fc)
            bfr[fc] = *(const bf16x8*)&Bs[wn + fc * 16 + l15][lhi * 8];
#pragma unroll
        for (int fr = 0; fr < 4; ++fr)
#pragma unroll
            for (int fc = 0; fc < 4; ++fc)
                acc[fr][fc] = __builtin_amdgcn_mfma_f32_16x16x32_bf16(af[fr], bfr[fc], acc[fr][fc], 0, 0, 0);
        __syncthreads();
    }
#pragma unroll
    for (int fc = 0; fc < 4; ++fc) {
        int col = n0 + wn + fc * 16 + l15;
        float bv = bias[col];
#pragma unroll
        for (int fr = 0; fr < 4; ++fr) {
#pragma unroll
            for (int r = 0; r < 4; ++r) {
                int row = m0 + wm + fr * 16 + lhi * 4 + r;
                C16[(long long)row * N + col] = f2b(acc[fr][fc][r] + bv);
            }
        }
    }
}

// ---------------- fused dual convT(1,8) tap-reduce: tout = coreT + coreF + biases + ag --
// layouts: YF seq n=b*64+t (L=25, pos f); YT seq n=b*32+f (L=57, pos t)
__global__ void dual_reduce_k(const ushort* __restrict__ YF, const ushort* __restrict__ YT,
                              const float* __restrict__ f_ctb, const float* __restrict__ t_ctb,
                              const float* __restrict__ ag, float* __restrict__ tout)
{
    int gid = blockIdx.x * blockDim.x + threadIdx.x;   // 2,097,152
    int d = gid & 63; int rest = gid >> 6;
    int f = rest & 31; rest >>= 5;
    int t = rest & 63; int b = rest >> 6;
    float v = f_ctb[d] + t_ctb[d];
    long long ybF = ((long long)(b * 64 + t)) * LF;
    long long ybT = ((long long)(b * 32 + f)) * LT;
#pragma unroll
    for (int tap = 0; tap < 8; ++tap) {
        int lf = f + tap - 7;
        if (lf >= 0 && lf < LF) v += b2f(YF[(ybF + lf) * 512 + tap * 64 + d]);
        int lt = t + tap - 7;
        if (lt >= 0 && lt < LT) v += b2f(YT[(ybT + lt) * 512 + tap * 64 + d]);
    }
    long long oi = (((long long)(b * 64 + d)) * 64 + t) * 32 + f;
    tout[oi] = v + ag[oi];
}

// ---------------- bf16 MFMA implicit GEMM over NCHW f32 activations ----------------
template<int BN>
__global__ __launch_bounds__(256) void mfma_nchw_k(
    const float* __restrict__ X, const ushort* __restrict__ WT,
    const float* __restrict__ bias, float* __restrict__ Y,
    int P, int N, int K)
{
    constexpr int FC = BN / 32;
    __shared__ ushort As[128][40];
    int p0 = blockIdx.x * 128;
    int n0 = blockIdx.y * BN;
    int b  = blockIdx.z;
    int tid = threadIdx.x, wave = tid >> 6, lane = tid & 63;
    int l15 = lane & 15, lhi = lane >> 4;
    int wm = (wave & 1) * 64, wn = (wave >> 1) * (BN / 2);
    f32x4 acc[4][FC] = {};
    const float* Xb = X + (long long)b * K * P;
    int kk_s = tid >> 3, pq_s = tid & 7;

    for (int k0 = 0; k0 < K; k0 += 32) {
        const float* xr = Xb + (long long)(k0 + kk_s) * P + p0;
#pragma unroll
        for (int j = 0; j < 4; ++j) {
            float4 v = *(const float4*)(xr + j * 32 + pq_s * 4);
            int pp = j * 32 + pq_s * 4;
            As[pp][kk_s]     = f2b(v.x);
            As[pp + 1][kk_s] = f2b(v.y);
            As[pp + 2][kk_s] = f2b(v.z);
            As[pp + 3][kk_s] = f2b(v.w);
        }
        __syncthreads();
        bf16x8 af[4], bfr[FC];
#pragma unroll
        for (int fr = 0; fr < 4; ++fr)
            af[fr] = *(const bf16x8*)&As[wm + fr * 16 + l15][lhi * 8];
#pragma unroll
        for (int fc = 0; fc < FC; ++fc)
            bfr[fc] = *(const bf16x8*)(WT + (long long)(n0 + wn + fc * 16 + l15) * K + k0 + lhi * 8);
#pragma unroll
        for (int fr = 0; fr < 4; ++fr)
#pragma unroll
            for (int fc = 0; fc < FC; ++fc)
                acc[fr][fc] = __builtin_amdgcn_mfma_f32_16x16x32_bf16(af[fr], bfr[fc], acc[fr][fc], 0, 0, 0);
        __syncthreads();
    }
#pragma unroll
    for (int fc = 0; fc < FC; ++fc) {
        int n = n0 + wn + fc * 16 + l15;
        float bv = bias[n];
        float* yr = Y + ((long long)(b * N + n)) * P + p0 + wm + lhi * 4;
#pragma unroll
        for (int fr = 0; fr < 4; ++fr) {
            float4 o;
            o.x = acc[fr][fc][0] + bv;
            o.y = acc[fr][fc][1] + bv;
            o.z = acc[fr][fc][2] + bv;
            o.w = acc[fr][fc][3] + bv;
            *(float4*)(yr + fr * 16) = o;
        }
    }
}

// ---------------- same but bf16 NCHW input (final conv) ----------------
__global__ __launch_bounds__(256) void mfma_nchw16_k(
    const ushort* __restrict__ X, const ushort* __restrict__ WT,
    const float* __restrict__ bias, float* __restrict__ Y,
    int P, int N, int K)
{
    constexpr int BN = 128, FC = 4;
    __shared__ ushort As[128][40];
    int p0 = blockIdx.x * 128;
    int n0 = blockIdx.y * BN;
    int b  = blockIdx.z;
    int tid = threadIdx.x, wave = tid >> 6, lane = tid & 63;
    int l15 = lane & 15, lhi = lane >> 4;
    int wm = (wave & 1) * 64, wn = (wave >> 1) * (BN / 2);
    f32x4 acc[4][FC] = {};
    const ushort* Xb = X + (long long)b * K * P;
    int kk_s = tid >> 3, pq_s = tid & 7;

    for (int k0 = 0; k0 < K; k0 += 32) {
        const ushort* xr = Xb + (long long)(k0 + kk_s) * P + p0 + pq_s * 16;
#pragma unroll
        for (int j = 0; j < 2; ++j) {
            uint4 v = *(const uint4*)(xr + j * 8);
            const ushort* e = (const ushort*)&v;
            int pp = pq_s * 16 + j * 8;
#pragma unroll
            for (int t = 0; t < 8; ++t) As[pp + t][kk_s] = e[t];
        }
        __syncthreads();
        bf16x8 af[4], bfr[FC];
#pragma unroll
        for (int fr = 0; fr < 4; ++fr)
            af[fr] = *(const bf16x8*)&As[wm + fr * 16 + l15][lhi * 8];
#pragma unroll
        for (int fc = 0; fc < FC; ++fc)
            bfr[fc] = *(const bf16x8*)(WT + (long long)(n0 + wn + fc * 16 + l15) * K + k0 + lhi * 8);
#pragma unroll
        for (int fr = 0; fr < 4; ++fr)
#pragma unroll
            for (int fc = 0; fc < FC; ++fc)
                acc[fr][fc] = __builtin_amdgcn_mfma_f32_16x16x32_bf16(af[fr], bfr[fc], acc[fr][fc], 0, 0, 0);
        __syncthreads();
    }
#pragma unroll
    for (int fc = 0; fc < FC; ++fc) {
        int n = n0 + wn + fc * 16 + l15;
        float bv = bias[n];
        float* yr = Y + ((long long)(b * N + n)) * P + p0 + wm + lhi * 4;
#pragma unroll
        for (int fr = 0; fr < 4; ++fr) {
            float4 o;
            o.x = acc[fr][fc][0] + bv;
            o.y = acc[fr][fc][1] + bv;
            o.z = acc[fr][fc][2] + bv;
            o.w = acc[fr][fc][3] + bv;
            *(float4*)(yr + fr * 16) = o;
        }
    }
}

// ---------------- 3x3 s2 p1 conv + ReLU as implicit bf16 MFMA GEMM ----------------
__global__ __launch_bounds__(256) void down_mfma_k(
    const float* __restrict__ in, const ushort* __restrict__ WT9,
    const float* __restrict__ bias, float* __restrict__ out,
    int Hi, int Wi)
{
    __shared__ ushort Is[289][64];
    int Ho = Hi >> 1, Wo = Wi >> 1;
    int ntx = Wo >> 3, nty = Ho >> 3;
    int tx = blockIdx.x % ntx; int rest = blockIdx.x / ntx;
    int ty = rest % nty; int b = rest / nty;
    int oy0 = ty * 8, ox0 = tx * 8;
    int iy0 = oy0 * 2 - 1, ix0 = ox0 * 2 - 1;
    int tid = threadIdx.x, wave = tid >> 6, lane = tid & 63;
    int l15 = lane & 15, lhi = lane >> 4;
    int wm = (wave & 1) * 32, wn = (wave >> 1) * 32;

    const float* ib = in + (long long)b * 64 * Hi * Wi;
    for (int i = tid; i < 289 * 64; i += 256) {
        int c = i / 289; int sp = i - c * 289;
        int r = sp / 17; int s = sp - r * 17;
        int iy = iy0 + r, ix = ix0 + s;
        float v = 0.f;
        if (iy >= 0 && iy < Hi && ix >= 0 && ix < Wi)
            v = ib[(long long)c * Hi * Wi + (long long)iy * Wi + ix];
        Is[sp][c ^ ((sp & 7) << 3)] = f2b(v);
    }
    __syncthreads();

    f32x4 acc[2][2] = {};
#pragma unroll
    for (int tap = 0; tap < 9; ++tap) {
        int kh = tap / 3, kw = tap - kh * 3;
#pragma unroll
        for (int half = 0; half < 2; ++half) {
            int c0 = half * 32 + lhi * 8;
            bf16x8 af[2], bw[2];
#pragma unroll
            for (int fr = 0; fr < 2; ++fr) {
                int p = wm + fr * 16 + l15;
                int sp = (2 * (p >> 3) + kh) * 17 + 2 * (p & 7) + kw;
                af[fr] = *(const bf16x8*)&Is[sp][c0 ^ ((sp & 7) << 3)];
            }
#pragma unroll
            for (int fc = 0; fc < 2; ++fc) {
                int d = wn + fc * 16 + l15;
                bw[fc] = *(const bf16x8*)(WT9 + (tap * 64 + d) * 64 + c0);
            }
#pragma unroll
            for (int fr = 0; fr < 2; ++fr)
#pragma unroll
                for (int fc = 0; fc < 2; ++fc)
                    acc[fr][fc] = __builtin_amdgcn_mfma_f32_16x16x32_bf16(af[fr], bw[fc], acc[fr][fc], 0, 0, 0);
        }
    }
#pragma unroll
    for (int fc = 0; fc < 2; ++fc) {
        int d = wn + fc * 16 + l15;
        float bv = bias[d];
        long long obase = ((long long)(b * 64 + d)) * Ho * Wo;
#pragma unroll
        for (int fr = 0; fr < 2; ++fr) {
#pragma unroll
            for (int r = 0; r < 4; ++r) {
                int p = wm + fr * 16 + lhi * 4 + r;
                int py = p >> 3, px = p & 7;
                out[obase + (long long)(oy0 + py) * Wo + ox0 + px] =
                    fmaxf(acc[fr][fc][r] + bv, 0.f);
            }
        }
    }
}

// ---------------- convT k=2 s=2 as MFMA; OUT16 selects bf16 output ----------------
template<int OUT16>
__global__ __launch_bounds__(256) void up_mfma_k(
    const float* __restrict__ in, const ushort* __restrict__ WT,
    const float* __restrict__ bias, const float* __restrict__ resid,
    float* __restrict__ out, ushort* __restrict__ o16, int P, int wsh)
{
    __shared__ ushort As[128][72];
    int p0 = blockIdx.x * 128;
    int n0 = blockIdx.y * 128;
    int b  = blockIdx.z;
    int tid = threadIdx.x, wave = tid >> 6, lane = tid & 63;
    int l15 = lane & 15, lhi = lane >> 4;
    int wm = (wave & 1) * 64, wn = (wave >> 1) * 64;
    int Wi = 1 << wsh;
    int Ho = ((P >> wsh) << 1), Wo = Wi << 1;

    int kk_s = tid >> 3, pq_s = tid & 7;
#pragma unroll
    for (int h = 0; h < 2; ++h) {
        int k = h * 32 + kk_s;
        const float* xr = in + ((long long)(b * 64 + k)) * P + p0 + pq_s * 16;
#pragma unroll
        for (int j = 0; j < 4; ++j) {
            float4 v = *(const float4*)(xr + j * 4);
            int pp = pq_s * 16 + j * 4;
            As[pp][k]     = f2b(v.x);
            As[pp + 1][k] = f2b(v.y);
            As[pp + 2][k] = f2b(v.z);
            As[pp + 3][k] = f2b(v.w);
        }
    }
    __syncthreads();

    f32x4 acc[4][4] = {};
#pragma unroll
    for (int c = 0; c < 2; ++c) {
        bf16x8 af[4], bfr[4];
#pragma unroll
        for (int fr = 0; fr < 4; ++fr)
            af[fr] = *(const bf16x8*)&As[wm + fr * 16 + l15][c * 32 + lhi * 8];
#pragma unroll
        for (int fc = 0; fc < 4; ++fc)
            bfr[fc] = *(const bf16x8*)(WT + (long long)(n0 + wn + fc * 16 + l15) * 64 + c * 32 + lhi * 8);
#pragma unroll
        for (int fr = 0; fr < 4; ++fr)
#pragma unroll
            for (int fc = 0; fc < 4; ++fc)
                acc[fr][fc] = __builtin_amdgcn_mfma_f32_16x16x32_bf16(af[fr], bfr[fc], acc[fr][fc], 0, 0, 0);
    }

#pragma unroll
    for (int fc = 0; fc < 4; ++fc) {
        int n = n0 + wn + fc * 16 + l15;
        int parity = n >> 6, d = n & 63;
        int py = parity >> 1, px = parity & 1;
        float bv = bias[d];
        const long long obase = ((long long)(b * 64 + d)) * Ho * Wo;
#pragma unroll
        for (int fr = 0; fr < 4; ++fr) {
#pragma unroll
            for (int r = 0; r < 4; ++r) {
                int p = p0 + wm + fr * 16 + lhi * 4 + r;
                int iy = p >> wsh, ix = p & (Wi - 1);
                long long oi = obase + (long long)(2 * iy + py) * Wo + 2 * ix + px;
                float v = acc[fr][fc][r] + bv + resid[oi];
                if (OUT16) o16[oi] = f2b(v);
                else       out[oi] = v;
            }
        }
    }
}

// ---------------- qkv projection -> bf16 [b][p][192] ----------------
__global__ __launch_bounds__(256) void mfma_qkv_k(
    const float* __restrict__ X, const ushort* __restrict__ WT,
    const float* __restrict__ bias, ushort* __restrict__ C16)
{
    __shared__ ushort As[128][72];
    int p0 = blockIdx.x * 128;
    int b  = blockIdx.z;
    int tid = threadIdx.x, wave = tid >> 6, lane = tid & 63;
    int l15 = lane & 15, lhi = lane >> 4;
    int wm = (wave & 1) * 64, wn = (wave >> 1) * 96;

    int kk_s = tid >> 3, pq_s = tid & 7;
#pragma unroll
    for (int h = 0; h < 2; ++h) {
        int k = h * 32 + kk_s;
        const float* xr = X + ((long long)(b * 64 + k)) * P4 + p0 + pq_s * 16;
#pragma unroll
        for (int j = 0; j < 4; ++j) {
            float4 v = *(const float4*)(xr + j * 4);
            int pp = pq_s * 16 + j * 4;
            As[pp][k]     = f2b(v.x);
            As[pp + 1][k] = f2b(v.y);
            As[pp + 2][k] = f2b(v.z);
            As[pp + 3][k] = f2b(v.w);
        }
    }
    __syncthreads();

    f32x4 acc[4][6] = {};
#pragma unroll
    for (int c = 0; c < 2; ++c) {
        bf16x8 af[4], bfr[6];
#pragma unroll
        for (int fr = 0; fr < 4; ++fr)
            af[fr] = *(const bf16x8*)&As[wm + fr * 16 + l15][c * 32 + lhi * 8];
#pragma unroll
        for (int fc = 0; fc < 6; ++fc)
            bfr[fc] = *(const bf16x8*)(WT + (long long)(wn + fc * 16 + l15) * 64 + c * 32 + lhi * 8);
#pragma unroll
        for (int fr = 0; fr < 4; ++fr)
#pragma unroll
            for (int fc = 0; fc < 6; ++fc)
                acc[fr][fc] = __builtin_amdgcn_mfma_f32_16x16x32_bf16(af[fr], bfr[fc], acc[fr][fc], 0, 0, 0);
    }
#pragma unroll
    for (int fc = 0; fc < 6; ++fc) {
        int n = wn + fc * 16 + l15;
        float bv = bias[n];
#pragma unroll
        for (int fr = 0; fr < 4; ++fr)
#pragma unroll
            for (int r = 0; r < 4; ++r) {
                int p = p0 + wm + fr * 16 + lhi * 4 + r;
                C16[((long long)(b * P4 + p)) * 192 + n] = f2b(acc[fr][fc][r] + bv);
            }
    }
}

// ---------------- attention out-proj ----------------
__global__ __launch_bounds__(256) void mfma_attnout_k(
    const float* __restrict__ A, const ushort* __restrict__ owT,
    const float* __restrict__ ob, const float* __restrict__ resid,
    float* __restrict__ dp)
{
    __shared__ ushort As[128][72];
    int p0 = blockIdx.x * 128;
    int b  = blockIdx.z;
    int tid = threadIdx.x, wave = tid >> 6, lane = tid & 63;
    int l15 = lane & 15, lhi = lane >> 4;
    int wm = (wave & 1) * 64, wn = (wave >> 1) * 32;

    int rs = tid >> 2, qs = tid & 3;
#pragma unroll
    for (int h = 0; h < 2; ++h) {
        int row = h * 64 + rs;
        const float* ar = A + ((long long)(b * P4 + p0 + row)) * 64 + qs * 16;
#pragma unroll
        for (int j = 0; j < 4; ++j) {
            float4 v = *(const float4*)(ar + j * 4);
            int c = qs * 16 + j * 4;
            *(unsigned*)&As[row][c]     = cvtpk_bf16(v.x, v.y);
            *(unsigned*)&As[row][c + 2] = cvtpk_bf16(v.z, v.w);
        }
    }
    __syncthreads();

    f32x4 acc[4][2] = {};
#pragma unroll
    for (int c = 0; c < 2; ++c) {
        bf16x8 af[4], bfr[2];
#pragma unroll
        for (int fr = 0; fr < 4; ++fr)
            af[fr] = *(const bf16x8*)&As[wm + fr * 16 + l15][c * 32 + lhi * 8];
#pragma unroll
        for (int fc = 0; fc < 2; ++fc)
            bfr[fc] = *(const bf16x8*)(owT + (long long)(wn + fc * 16 + l15) * 64 + c * 32 + lhi * 8);
#pragma unroll
        for (int fr = 0; fr < 4; ++fr)
#pragma unroll
            for (int fc = 0; fc < 2; ++fc)
                acc[fr][fc] = __builtin_amdgcn_mfma_f32_16x16x32_bf16(af[fr], bfr[fc], acc[fr][fc], 0, 0, 0);
    }
#pragma unroll
    for (int fc = 0; fc < 2; ++fc) {
        int n = wn + fc * 16 + l15;
        float bv = ob[n];
        long long base = ((long long)(b * 64 + n)) * P4;
#pragma unroll
        for (int fr = 0; fr < 4; ++fr) {
            int p = p0 + wm + fr * 16 + lhi * 4;
            float4 rv = *(const float4*)(resid + base + p);
            float4 o;
            o.x = acc[fr][fc][0] + bv + rv.x;
            o.y = acc[fr][fc][1] + bv + rv.y;
            o.z = acc[fr][fc][2] + bv + rv.z;
            o.w = acc[fr][fc][3] + bv + rv.w;
            *(float4*)(dp + base + p) = o;
        }
    }
}

// ---------------- MFMA flash attention (dh=16, 4 heads), bf16 qkv input ----------------
__global__ __launch_bounds__(256) void attn_mfma_k(const ushort* __restrict__ qkv,
                                                   float* __restrict__ out)
{
    __shared__ ushort Qs[128][40];
    __shared__ ushort Ks[64][40];
    __shared__ ushort VsT[16][72];
    __shared__ ushort Ps[128][72];
    int qt = blockIdx.x, h = blockIdx.y, b = blockIdx.z;
    int tid = threadIdx.x, wave = tid >> 6, lane = tid & 63;
    int l15 = lane & 15, lhi = lane >> 4;
    int q0 = wave * 32;

    for (int i = tid; i < 1024; i += 256) {
        int row = i >> 3, c = i & 7;
        *(unsigned*)&Qs[row][16 + c * 2] = 0u;
    }
    for (int i = tid; i < 512; i += 256) {
        int row = i >> 3, c = i & 7;
        *(unsigned*)&Ks[row][16 + c * 2] = 0u;
    }
    {
        const ushort* qp = qkv + ((long long)(b * P4 + qt * 128)) * 192 + h * 16;
        for (int i = tid; i < 2048; i += 256) {
            int row = i >> 4, d = i & 15;
            Qs[row][d] = f2b(b2f(qp[row * 192 + d]) * 0.25f);
        }
    }
    __syncthreads();

    float mmax[2] = {-1e30f, -1e30f};
    float lsum[2] = {0.f, 0.f};
    f32x4 oacc[2] = {};

    for (int k0 = 0; k0 < P4; k0 += 64) {
        const ushort* kp = qkv + ((long long)(b * P4 + k0)) * 192 + 64 + h * 16;
        for (int i = tid; i < 1024; i += 256) {
            int key = i >> 4, d = i & 15;
            Ks[key][d]  = kp[key * 192 + d];
            VsT[d][key] = kp[key * 192 + 64 + d];
        }
        __syncthreads();

        bf16x8 bq[2];
        bq[0] = *(const bf16x8*)&Qs[q0 + l15][lhi * 8];
        bq[1] = *(const bf16x8*)&Qs[q0 + 16 + l15][lhi * 8];
        f32x4 s[4][2];
#pragma unroll
        for (int fr = 0; fr < 4; ++fr) {
            bf16x8 ak = *(const bf16x8*)&Ks[fr * 16 + l15][lhi * 8];
            f32x4 z = {};
            s[fr][0] = __builtin_amdgcn_mfma_f32_16x16x32_bf16(ak, bq[0], z, 0, 0, 0);
            s[fr][1] = __builtin_amdgcn_mfma_f32_16x16x32_bf16(ak, bq[1], z, 0, 0, 0);
        }
#pragma unroll
        for (int fc = 0; fc < 2; ++fc) {
            float m = s[0][fc][0];
#pragma unroll
            for (int fr = 0; fr < 4; ++fr)
#pragma unroll
                for (int r = 0; r < 4; ++r) m = fmaxf(m, s[fr][fc][r]);
            m = fmaxf(m, __shfl_xor(m, 16));
            m = fmaxf(m, __shfl_xor(m, 32));
            float nm = fmaxf(mmax[fc], m);
            float corr = __expf(mmax[fc] - nm);
            mmax[fc] = nm;
            float ps = 0.f;
#pragma unroll
            for (int fr = 0; fr < 4; ++fr)
#pragma unroll
                for (int r = 0; r < 4; ++r) {
                    float p = __expf(s[fr][fc][r] - nm);
                    s[fr][fc][r] = p;
                    ps += p;
                }
            lsum[fc] = lsum[fc] * corr + ps;
#pragma unroll
            for (int r = 0; r < 4; ++r) oacc[fc][r] *= corr;
        }
#pragma unroll
        for (int fc = 0; fc < 2; ++fc)
#pragma unroll
            for (int fr = 0; fr < 4; ++fr) {
                uint2 pk;
                pk.x = cvtpk_bf16(s[fr][fc][0], s[fr][fc][1]);
                pk.y = cvtpk_bf16(s[fr][fc][2], s[fr][fc][3]);
                *(uint2*)&Ps[q0 + fc * 16 + l15][fr * 16 + lhi * 4] = pk;
            }
#pragma unroll
        for (int ks = 0; ks < 2; ++ks) {
            bf16x8 av = *(const bf16x8*)&VsT[l15][ks * 32 + lhi * 8];
#pragma unroll
            for (int fc = 0; fc < 2; ++fc) {
                bf16x8 bp = *(const bf16x8*)&Ps[q0 + fc * 16 + l15][ks * 32 + lhi * 8];
                oacc[fc] = __builtin_amdgcn_mfma_f32_16x16x32_bf16(av, bp, oacc[fc], 0, 0, 0);
            }
        }
        __syncthreads();
    }
#pragma unroll
    for (int fc = 0; fc < 2; ++fc) {
        float L = lsum[fc];
        L += __shfl_xor(L, 16);
        L += __shfl_xor(L, 32);
        float inv = 1.f / L;
        int q = qt * 128 + q0 + fc * 16 + l15;
        float* op = out + ((long long)(b * P4 + q)) * 64 + h * 16 + lhi * 4;
#pragma unroll
        for (int r = 0; r < 4; ++r) op[r] = oacc[fc][r] * inv;
    }
}

// ---------------- host launch ----------------
extern "C" void kernel_launch(void* const* d_in, const int* in_sizes, int n_in,
                              void* d_out, int out_size, void* d_ws, size_t ws_size,
                              hipStream_t stream)
{
    const float* A_in  = (const float*)d_in[0];
    const float* cw    = (const float*)d_in[1];
    const float* cb    = (const float*)d_in[2];
    const float* dw0   = (const float*)d_in[3];
    const float* db0   = (const float*)d_in[4];
    const float* dw1   = (const float*)d_in[5];
    const float* db1   = (const float*)d_in[6];
    const float* f_Wx  = (const float*)d_in[7];
    const float* f_bf  = (const float*)d_in[8];
    const float* f_br  = (const float*)d_in[9];
    const float* f_Whw = (const float*)d_in[10];
    const float* f_pw  = (const float*)d_in[11];
    const float* f_pb  = (const float*)d_in[12];
    const float* f_ctw = (const float*)d_in[13];
    const float* f_ctb = (const float*)d_in[14];
    const float* t_Wx  = (const float*)d_in[15];
    const float* t_bf  = (const float*)d_in[16];
    const float* t_br  = (const float*)d_in[17];
    const float* t_Whw = (const float*)d_in[18];
    const float* t_pw  = (const float*)d_in[19];
    const float* t_pb  = (const float*)d_in[20];
    const float* t_ctw = (const float*)d_in[21];
    const float* t_ctb = (const float*)d_in[22];
    const float* qkv_w = (const float*)d_in[23];
    const float* qkv_b = (const float*)d_in[24];
    const float* ow    = (const float*)d_in[25];
    const float* ob    = (const float*)d_in[26];
    const float* upw0  = (const float*)d_in[27];
    const float* upb0  = (const float*)d_in[28];
    const float* upw1  = (const float*)d_in[29];
    const float* upb1  = (const float*)d_in[30];
    const float* fw    = (const float*)d_in[31];
    const float* fb    = (const float*)d_in[32];

    float* ws  = (float*)d_ws;
    float* out = (float*)d_out;

    // ---- workspace layout (f32 units) ----
    float* ag    = ws + 0;          // 1,048,576
    float* x1    = ws + 1048576;    // 4,194,304
    // phase 1: unfold inputs
    float* uFf   = ws + 5242880;    // 3,276,800 (bf16)
    float* uTf   = ws + 8519680;    // 3,735,552 (bf16)
    // gate planes (bf16 now; offsets kept from r11, extra space unused)
    float* GxtF  = ws + 12255232;
    float* GxhF  = ws + 15532032;
    float* GxtT  = ws + 18808832;
    float* GxhT  = ws + 22544384;
    float* GfFf  = ws + 26279936;
    float* GrFf  = ws + 27918336;
    float* GfTf  = ws + 29556736;
    float* GrTf  = ws + 31424512;
    float* hFf   = ws + 33292288;
    float* hTf   = ws + 34930688;   // -> ends 36,798,464
    // overlays:
    float* YF16f = ws + 5242880;    // 3,276,800 (bf16 Y, over uF; after scan)
    float* YT16f = ws + 8519680;    // 3,735,552 (bf16 Y, over uT)
    float* y016f = ws + 19267584;   // 8,388,608 (over GxtT/GxhT, after scan)
    float* y1    = ws + 12255232;   // 4,194,304 (over GxtF/GxhF, after gemmW)
    // weights + tail:
    float* pwFf  = ws + 36798464;
    float* pwTf  = ws + 36864000;
    float* w3Ff  = ws + 36929536;
    float* w3Tf  = ws + 36995072;
    float* b3Ff  = ws + 37060608;
    float* b3Tf  = ws + 37061120;
    float* wctFf = ws + 37061632;
    float* wctTf = ws + 37192704;
    float* wcaFf = ws + 37323776;
    float* wcaTf = ws + 37585920;
    float* cw16f = ws + 37848064;
    float* fw16f = ws + 37856256;
    float* wup0f = ws + 37864448;
    float* wup1f = ws + 37872640;
    float* qkvwf = ws + 37880832;
    float* owtf  = ws + 37886976;
    float* wdw0f = ws + 37889024;
    float* wdw1f = ws + 37907456;   // -> 37,925,888
    float* tout  = ws + 37925888;   // 1,048,576
    float* qkvbf = ws + 38974464;   // 1,572,864
    float* attnO = ws + 40547328;   // 1,048,576
    float* dp    = ws + 41595904;   // 1,048,576 -> total 42,644,480 f32 (~171 MB)

    ushort* uF     = (ushort*)uFf;
    ushort* uT     = (ushort*)uTf;
    ushort* GxtF16 = (ushort*)GxtF;
    ushort* GxhF16 = (ushort*)GxhF;
    ushort* GxtT16 = (ushort*)GxtT;
    ushort* GxhT16 = (ushort*)GxhT;
    ushort* GfF    = (ushort*)GfFf;
    ushort* GrF    = (ushort*)GrFf;
    ushort* GfT    = (ushort*)GfTf;
    ushort* GrT    = (ushort*)GrTf;
    ushort* hF     = (ushort*)hFf;
    ushort* hT     = (ushort*)hTf;
    ushort* YF16   = (ushort*)YF16f;
    ushort* YT16   = (ushort*)YT16f;
    ushort* y016   = (ushort*)y016f;
    ushort* pwF16  = (ushort*)pwFf;
    ushort* pwT16  = (ushort*)pwTf;
    ushort* W3F    = (ushort*)w3Ff;
    ushort* W3T_   = (ushort*)w3Tf;
    ushort* WctF   = (ushort*)wctFf;
    ushort* WctT_  = (ushort*)wctTf;
    ushort* WcatF  = (ushort*)wcaFf;
    ushort* WcatTm = (ushort*)wcaTf;
    ushort* qkv16  = (ushort*)qkvbf;
    ushort* cw16   = (ushort*)cw16f;
    ushort* fw16   = (ushort*)fw16f;
    ushort* WupT0  = (ushort*)wup0f;
    ushort* WupT1  = (ushort*)wup1f;
    ushort* qkvwT  = (ushort*)qkvwf;
    ushort* owT    = (ushort*)owtf;
    ushort* WT9d0  = (ushort*)wdw0f;
    ushort* WT9d1  = (ushort*)wdw1f;
    float*  x0     = out;           // x0 parked in d_out

    dim3 blk(256);

    // ---- weight packs + W3/bias3 precompute ----
    pack_all_k<<<dim3(7776), blk, 0, stream>>>(
        cw, fw, upw0, upw1, qkv_w, ow, dw0, dw1, f_pw, t_pw, f_ctw, t_ctw,
        f_Wx, f_Whw, t_Wx, t_Whw,
        cw16, fw16, WupT0, WupT1, qkvwT, owT, WT9d0, WT9d1,
        pwF16, pwT16, WctF, WctT_, WcatF, WcatTm);
    w3_gemm_k<<<dim3(4, 2, 2), blk, 0, stream>>>(pwF16, WctF, pwT16, WctT_, W3F, W3T_);
    bias3_red_k<<<dim3(512, 2), blk, 0, stream>>>(f_pb, f_ctw, t_pb, t_ctw, b3Ff, b3Tf);

    // 1. compress
    mfma_nchw_k<64><<<dim3(256, 1, 8), blk, 0, stream>>>(A_in, cw16, cb, x0, 32768, 64, 256);

    // 2-3. downsample
    down_mfma_k<<<dim3(1024), blk, 0, stream>>>(x0, WT9d0, db0, x1, TT, FF);
    down_mfma_k<<<dim3(256), blk, 0, stream>>>(x1, WT9d1, db1, ag, T2, F2);

    // ---- both pathways, batched ----
    unfold_both_k<<<dim3(54784), blk, 0, stream>>>(ag, uF, uT);
    gates_fused_k<<<dim3(8, 214), blk, 0, stream>>>(uF, uT, WcatF, WcatTm,
        GxtF16, GxhF16, GfF, GrF, GxtT16, GxhT16, GfT, GrT, f_bf, f_br, t_bf, t_br);
    sru_scan_both_k<<<dim3(768), blk, 0, stream>>>(GxtF16, GxhF16, GfF, GrF, hF,
                                                   GxtT16, GxhT16, GfT, GrT, hT);
    gemmW_both_k<<<dim3(4, 214), blk, 0, stream>>>(hF, W3F, YF16, b3Ff,
                                                   hT, W3T_, YT16, b3Tf);
    dual_reduce_k<<<dim3(8192), blk, 0, stream>>>(YF16, YT16, f_ctb, t_ctb, ag, tout);

    // ---- attention ----
    mfma_qkv_k<<<dim3(16, 1, 8), blk, 0, stream>>>(tout, qkvwT, qkv_b, qkv16);
    attn_mfma_k<<<dim3(16, NHEADS, BB), blk, 0, stream>>>(qkv16, attnO);
    mfma_attnout_k<<<dim3(16, 1, 8), blk, 0, stream>>>(attnO, owT, ob, tout, dp);

    // ---- reconstruction ----
    up_mfma_k<0><<<dim3(16, 2, 8), blk, 0, stream>>>(dp, WupT0, upb0, x1, y1, nullptr, 2048, 5);
    up_mfma_k<1><<<dim3(64, 2, 8), blk, 0, stream>>>(y1, WupT1, upb1, x0, nullptr, y016, 8192, 6);

    // final 1x1 conv (bf16 NCHW input)
    mfma_nchw16_k<<<dim3(256, 2, 8), blk, 0, stream>>>(y016, fw16, fb, out, 32768, 256, 64);
}

// Round 13
// 671.053 us; speedup vs baseline: 1.0136x; 1.0136x over previous
//
#include <hip/hip_runtime.h>

// ---------------- problem constants ----------------
#define BB 8
#define CC 256
#define TT 256
#define FF 128
#define DD 64
#define HH 128
#define NHEADS 4
#define KK 8
#define II 512            // D*K
#define T2 128
#define F2 64
#define T4 64
#define F4 32
#define P4 2048           // T4*F4

// freq pathway: N=512 seqs, L=25 ; time pathway: N=256 seqs, L=57
#define LF 25
#define LT 57
#define MF (512*LF)       // 12800 (= 100*128)
#define MT (256*LT)       // 14592 (= 114*128)

typedef __attribute__((ext_vector_type(8))) short bf16x8;
typedef __attribute__((ext_vector_type(4))) float f32x4;

__device__ __forceinline__ ushort f2b(float x) {
    unsigned u = __float_as_uint(x);
    unsigned r = (u + 0x7FFFu + ((u >> 16) & 1u)) >> 16;
    return (ushort)r;
}
__device__ __forceinline__ float b2f(ushort x) {
    return __uint_as_float(((unsigned)x) << 16);
}
__device__ __forceinline__ unsigned cvtpk_bf16(float lo, float hi) {
    unsigned r;
    asm("v_cvt_pk_bf16_f32 %0, %1, %2" : "=v"(r) : "v"(lo), "v"(hi));
    return r;
}

// ---------------- ONE mega weight-pack kernel ----------------
__global__ __launch_bounds__(256) void pack_all_k(
    const float* __restrict__ cw, const float* __restrict__ fw,
    const float* __restrict__ upw0, const float* __restrict__ upw1,
    const float* __restrict__ qkv_w, const float* __restrict__ ow,
    const float* __restrict__ dw0, const float* __restrict__ dw1,
    const float* __restrict__ f_pw, const float* __restrict__ t_pw,
    const float* __restrict__ f_ctw, const float* __restrict__ t_ctw,
    const float* __restrict__ f_Wx, const float* __restrict__ f_Whw,
    const float* __restrict__ t_Wx, const float* __restrict__ t_Whw,
    ushort* __restrict__ cw16, ushort* __restrict__ fw16,
    ushort* __restrict__ WupT0, ushort* __restrict__ WupT1,
    ushort* __restrict__ qkvwT, ushort* __restrict__ owT,
    ushort* __restrict__ WT9d0, ushort* __restrict__ WT9d1,
    ushort* __restrict__ pwF16, ushort* __restrict__ pwT16,
    ushort* __restrict__ WctF, ushort* __restrict__ WctT_,
    ushort* __restrict__ WcatF, ushort* __restrict__ WcatTm)
{
    int bid = blockIdx.x, tid = threadIdx.x;
    if (bid < 64)        { int g = bid * 256 + tid; cw16[g] = f2b(cw[g]); return; }
    if (bid < 128)       { int g = (bid - 64) * 256 + tid; fw16[g] = f2b(fw[g]); return; }
    if (bid < 256) {     // upw0 / upw1
        const float* w = (bid < 192) ? upw0 : upw1;
        ushort* O = (bid < 192) ? WupT0 : WupT1;
        int g = ((bid - 128) & 63) * 256 + tid;
        int c = g & 63; int n = g >> 6;
        int parity = n >> 6, d = n & 63;
        O[g] = f2b(w[((d * 64 + c) * 2 + (1 - (parity >> 1))) * 2 + (1 - (parity & 1))]);
        return;
    }
    if (bid < 304) {     // qkv_w^T: K=64, N=192
        int g = (bid - 256) * 256 + tid;
        int k = g & 63, n = g >> 6;
        qkvwT[g] = f2b(qkv_w[k * 192 + n]); return;
    }
    if (bid < 320) {     // ow^T: 64x64
        int g = (bid - 304) * 256 + tid;
        int k = g & 63, n = g >> 6;
        owT[g] = f2b(ow[k * 64 + n]); return;
    }
    if (bid < 608) {     // dw9 x2
        const float* w = (bid < 464) ? dw0 : dw1;
        ushort* O = (bid < 464) ? WT9d0 : WT9d1;
        int g = ((bid - 320) % 144) * 256 + tid;
        int c = g & 63; int rest = g >> 6;
        int d = rest & 63; int tap = rest >> 6;
        O[g] = f2b(w[(d * 64 + c) * 9 + tap]); return;
    }
    if (bid < 1632) {    // pw x2 (131072 each)
        const float* w = (bid < 1120) ? f_pw : t_pw;
        ushort* O = (bid < 1120) ? pwF16 : pwT16;
        int g = ((bid - 608) % 512) * 256 + tid;
        O[g] = f2b(w[g]); return;
    }
    if (bid < 3680) {    // wct2T x2 (262144 each)
        const float* ctw = (bid < 2656) ? f_ctw : t_ctw;
        ushort* O = (bid < 2656) ? WctF : WctT_;
        int g = ((bid - 1632) % 1024) * 256 + tid;
        int k = g & 511; int n = g >> 9;
        int tap = n >> 6, d = n & 63;
        O[g] = f2b(ctw[((d * 512) + k) * 8 + tap]); return;
    }
    {                    // wcatT x2 (524288 each)
        const float* Wx  = (bid < 5728) ? f_Wx  : t_Wx;
        const float* Whw = (bid < 5728) ? f_Whw : t_Whw;
        ushort* O = (bid < 5728) ? WcatF : WcatTm;
        int g = ((bid - 3680) % 2048) * 256 + tid;
        int k = g & 511; int n = g >> 9;
        int dir = n >> 9; int c = n & 511;
        float v = (c < 384) ? Wx[(dir * 512 + k) * 384 + c]
                            : Whw[(dir * 512 + k) * 128 + (c - 384)];
        O[g] = f2b(v);
    }
}

// ---------------- W3 = pw @ W2 for BOTH pathways ----------------
__global__ __launch_bounds__(256) void w3_gemm_k(
    const ushort* __restrict__ pwA, const ushort* __restrict__ wctA,
    const ushort* __restrict__ pwB, const ushort* __restrict__ wctB,
    ushort* __restrict__ w3A, ushort* __restrict__ w3B)
{
    const int M = 256, K = 512;
    const ushort* A16  = blockIdx.z ? pwB  : pwA;
    const ushort* BT16 = blockIdx.z ? wctB : wctA;
    ushort* C16        = blockIdx.z ? w3B  : w3A;
    __shared__ ushort As[128][40];
    __shared__ ushort Bs[128][40];
    int m0 = blockIdx.y * 128, n0 = blockIdx.x * 128;
    int tid = threadIdx.x;
    int wave = tid >> 6, lane = tid & 63;
    int wm = (wave & 1) * 64, wn = (wave >> 1) * 64;
    int l15 = lane & 15, lhi = lane >> 4;
    f32x4 acc[4][4] = {};
    int rs = tid >> 2, qs = tid & 3;

    for (int k0 = 0; k0 < K; k0 += 32) {
        *(uint4*)&As[rs][qs * 8]      = *(const uint4*)(A16 + (long long)(m0 + rs) * K + k0 + qs * 8);
        *(uint4*)&As[rs + 64][qs * 8] = *(const uint4*)(A16 + (long long)(m0 + rs + 64) * K + k0 + qs * 8);
        *(uint4*)&Bs[rs][qs * 8]      = *(const uint4*)(BT16 + (long long)(n0 + rs) * K + k0 + qs * 8);
        *(uint4*)&Bs[rs + 64][qs * 8] = *(const uint4*)(BT16 + (long long)(n0 + rs + 64) * K + k0 + qs * 8);
        __syncthreads();
        bf16x8 af[4], bfr[4];
#pragma unroll
        for (int fr = 0; fr < 4; ++fr)
            af[fr] = *(const bf16x8*)&As[wm + fr * 16 + l15][lhi * 8];
#pragma unroll
        for (int fc = 0; fc < 4; ++fc)
            bfr[fc] = *(const bf16x8*)&Bs[wn + fc * 16 + l15][lhi * 8];
#pragma unroll
        for (int fr = 0; fr < 4; ++fr)
#pragma unroll
            for (int fc = 0; fc < 4; ++fc)
                acc[fr][fc] = __builtin_amdgcn_mfma_f32_16x16x32_bf16(af[fr], bfr[fc], acc[fr][fc], 0, 0, 0);
        __syncthreads();
    }
#pragma unroll
    for (int fr = 0; fr < 4; ++fr)
#pragma unroll
        for (int fc = 0; fc < 4; ++fc) {
            int col = n0 + wn + fc * 16 + l15;
#pragma unroll
            for (int r = 0; r < 4; ++r) {
                int row = m0 + wm + fr * 16 + lhi * 4 + r;
                C16[(long long)col * M + row] = f2b(acc[fr][fc][r]);
            }
        }
}

// bias3[n] = sum_i pb[i] * W2[i][n]
__global__ void bias3_red_k(const float* __restrict__ pbF, const float* __restrict__ ctwF,
                            const float* __restrict__ pbT, const float* __restrict__ ctwT,
                            float* __restrict__ b3F, float* __restrict__ b3T)
{
    int n = blockIdx.x; int path = blockIdx.y;
    const float* pb  = path ? pbT  : pbF;
    const float* ctw = path ? ctwT : ctwF;
    float* b3        = path ? b3T  : b3F;
    int d = n & 63, tap = n >> 6;
    int tid = threadIdx.x;
    float s = 0.f;
    for (int i = tid; i < 512; i += 256)
        s += pb[i] * ctw[(d * 512 + i) * 8 + tap];
    __shared__ float red[256];
    red[tid] = s; __syncthreads();
    for (int st = 128; st > 0; st >>= 1) {
        if (tid < st) red[tid] += red[tid + st];
        __syncthreads();
    }
    if (tid == 0) b3[n] = red[0];
}

// ---------------- unfold BOTH pathways in one launch -> bf16 ----------------
__global__ void unfold_both_k(const float* __restrict__ ag,
                              ushort* __restrict__ uF, ushort* __restrict__ uT)
{
    long long gid = (long long)blockIdx.x * blockDim.x + threadIdx.x;
    if (gid < (long long)MF * II) {
        int ch = (int)(gid & 511); int row = (int)(gid >> 9);
        int b = row / (T4 * LF); int rem = row - b * (T4 * LF);
        int t = rem / LF; int l = rem - t * LF;
        int d = ch >> 3, i = ch & 7;
        uF[gid] = f2b(ag[((long long)((b * DD + d) * T4 + t)) * F4 + l + i]);
    } else {
        long long g2 = gid - (long long)MF * II;
        int ch = (int)(g2 & 511); int row = (int)(g2 >> 9);
        int b = row / (F4 * LT); int rem = row - b * (F4 * LT);
        int tt = rem / LT; int l = rem - tt * LT;
        int d = ch >> 3, i = ch & 7;
        uT[g2] = f2b(ag[((long long)((b * DD + d) * T4 + (l + i))) * F4 + tt]);
    }
}

// ---------------- gates GEMM, BOTH pathways; f32 xt/xh planes, bf16 f/r ----------------
// grid (8, 100+114); by<100 -> freq, else time.
__global__ __launch_bounds__(256) void gates_fused_k(
    const ushort* __restrict__ uF, const ushort* __restrict__ uT,
    const ushort* __restrict__ WF, const ushort* __restrict__ WTm,
    float* __restrict__ GxtF, float* __restrict__ GxhF,
    ushort* __restrict__ GfF, ushort* __restrict__ GrF,
    float* __restrict__ GxtT, float* __restrict__ GxhT,
    ushort* __restrict__ GfT, ushort* __restrict__ GrT,
    const float* __restrict__ f_bf, const float* __restrict__ f_br,
    const float* __restrict__ t_bf, const float* __restrict__ t_br)
{
    __shared__ ushort As[128][40];
    __shared__ ushort Bs[128][40];
    const int K = 512;
    int by = blockIdx.y;
    bool tp = by >= 100;
    const ushort* A16 = tp ? uT : uF;
    const ushort* WT  = tp ? WTm : WF;
    float* Gxt = tp ? GxtT : GxtF;
    float* Gxh = tp ? GxhT : GxhF;
    ushort* Gf = tp ? GfT : GfF;
    ushort* Gr = tp ? GrT : GrF;
    const float* bfw = tp ? t_bf : f_bf;
    const float* brw = tp ? t_br : f_br;
    int m0 = (tp ? by - 100 : by) * 128;
    int n0 = blockIdx.x * 128;
    int tid = threadIdx.x, wave = tid >> 6, lane = tid & 63;
    int wm = (wave & 1) * 64, wn = (wave >> 1) * 64;
    int l15 = lane & 15, lhi = lane >> 4;
    f32x4 acc[4][4] = {};
    int rs = tid >> 2, qs = tid & 3;

    for (int k0 = 0; k0 < K; k0 += 32) {
        *(uint4*)&As[rs][qs * 8]      = *(const uint4*)(A16 + (long long)(m0 + rs) * K + k0 + qs * 8);
        *(uint4*)&As[rs + 64][qs * 8] = *(const uint4*)(A16 + (long long)(m0 + rs + 64) * K + k0 + qs * 8);
        *(uint4*)&Bs[rs][qs * 8]      = *(const uint4*)(WT + (long long)(n0 + rs) * K + k0 + qs * 8);
        *(uint4*)&Bs[rs + 64][qs * 8] = *(const uint4*)(WT + (long long)(n0 + rs + 64) * K + k0 + qs * 8);
        __syncthreads();
        bf16x8 af[4], bfr[4];
#pragma unroll
        for (int fr = 0; fr < 4; ++fr)
            af[fr] = *(const bf16x8*)&As[wm + fr * 16 + l15][lhi * 8];
#pragma unroll
        for (int fc = 0; fc < 4; ++fc)
            bfr[fc] = *(const bf16x8*)&Bs[wn + fc * 16 + l15][lhi * 8];
#pragma unroll
        for (int fr = 0; fr < 4; ++fr)
#pragma unroll
            for (int fc = 0; fc < 4; ++fc)
                acc[fr][fc] = __builtin_amdgcn_mfma_f32_16x16x32_bf16(af[fr], bfr[fc], acc[fr][fc], 0, 0, 0);
        __syncthreads();
    }
#pragma unroll
    for (int fc = 0; fc < 4; ++fc) {
        int col = n0 + wn + fc * 16 + l15;
        int dir = col >> 9, c = col & 511;
        int cls = c >> 7, h = c & 127;
        int dh = dir * 128 + h;
#pragma unroll
        for (int fr = 0; fr < 4; ++fr) {
#pragma unroll
            for (int r = 0; r < 4; ++r) {
                int row = m0 + wm + fr * 16 + lhi * 4 + r;
                long long idx = (long long)row * 256 + dh;
                float v = acc[fr][fc][r];
                if (cls == 0)      Gxt[idx] = v;
                else if (cls == 3) Gxh[idx] = v;
                else if (cls == 1) Gf[idx] = f2b(1.f / (1.f + __expf(-(v + bfw[dh]))));
                else               Gr[idx] = f2b(1.f / (1.f + __expf(-(v + brw[dh]))));
            }
        }
    }
}

// ---------------- SRU scan, BOTH pathways ----------------
__global__ void sru_scan_both_k(
    const float* __restrict__ GxtF, const float* __restrict__ GxhF,
    const ushort* __restrict__ GfF, const ushort* __restrict__ GrF,
    ushort* __restrict__ hF,
    const float* __restrict__ GxtT, const float* __restrict__ GxhT,
    const ushort* __restrict__ GfT, const ushort* __restrict__ GrT,
    ushort* __restrict__ hT)
{
    int gid = blockIdx.x * blockDim.x + threadIdx.x;
    const float *Gxt, *Gxh; const ushort *Gf, *Gr; ushort* hout; int L;
    if (gid < 512 * 256) {
        Gxt = GxtF; Gxh = GxhF; Gf = GfF; Gr = GrF; hout = hF; L = LF;
    } else {
        gid -= 512 * 256;
        Gxt = GxtT; Gxh = GxhT; Gf = GfT; Gr = GrT; hout = hT; L = LT;
    }
    int h = gid & 127; int dir = (gid >> 7) & 1; int n = gid >> 8;
    int dh = dir * 128 + h;
    float c = 0.f;
    for (int s = 0; s < L; ++s) {
        int l = dir ? (L - 1 - s) : s;
        long long off = (long long)(n * L + l) * 256 + dh;
        float xt = Gxt[off], xh = Gxh[off];
        float f = b2f(Gf[off]);
        float r = b2f(Gr[off]);
        c = f * c + (1.f - f) * xt;
        float hv = r * c + (1.f - r) * xh;
        hout[off] = f2b(hv);
    }
}

// ---------------- composite Y GEMM, BOTH pathways; bf16 Y output ----------------
// grid (4, 100+114)
__global__ __launch_bounds__(256) void gemmW_both_k(
    const ushort* __restrict__ hF, const ushort* __restrict__ W3F,
    ushort* __restrict__ YF, const float* __restrict__ b3F,
    const ushort* __restrict__ hT, const ushort* __restrict__ W3T,
    ushort* __restrict__ YT, const float* __restrict__ b3T)
{
    __shared__ ushort As[128][40];
    __shared__ ushort Bs[128][40];
    const int N = 512, K = 256;
    int by = blockIdx.y;
    bool tp = by >= 100;
    const ushort* A16 = tp ? hT : hF;
    const ushort* WT  = tp ? W3T : W3F;
    ushort* C16       = tp ? YT : YF;
    const float* bias = tp ? b3T : b3F;
    int m0 = (tp ? by - 100 : by) * 128;
    int n0 = blockIdx.x * 128;
    int tid = threadIdx.x, wave = tid >> 6, lane = tid & 63;
    int wm = (wave & 1) * 64, wn = (wave >> 1) * 64;
    int l15 = lane & 15, lhi = lane >> 4;
    f32x4 acc[4][4] = {};
    int rs = tid >> 2, qs = tid & 3;

    for (int k0 = 0; k0 < K; k0 += 32) {
        *(uint4*)&As[rs][qs * 8]      = *(const uint4*)(A16 + (long long)(m0 + rs) * K + k0 + qs * 8);
        *(uint4*)&As[rs + 64][qs * 8] = *(const uint4*)(A16 + (long long)(m0 + rs + 64) * K + k0 + qs * 8);
        *(uint4*)&Bs[rs][qs * 8]      = *(const uint4*)(WT + (long long)(n0 + rs) * K + k0 + qs * 8);
        *(uint4*)&Bs[rs + 64][qs * 8] = *(const uint4*)(WT + (long long)(n0 + rs + 64) * K + k0 + qs * 8);
        __syncthreads();
        bf16x8 af[4], bfr[4];
#pragma unroll
        for (int fr = 0; fr < 4; ++fr)
            af[fr] = *(const bf16x8*)&As[wm + fr * 16 + l15][lhi * 8];
#pragma unroll
        for (int fc = 0; fc < 4; ++fc)
            bfr[fc] = *(const bf16x8*)&Bs[wn + fc * 16 + l15][lhi * 8];
#pragma unroll
        for (int fr = 0; fr < 4; ++fr)
#pragma unroll
            for (int fc = 0; fc < 4; ++fc)
                acc[fr][fc] = __builtin_amdgcn_mfma_f32_16x16x32_bf16(af[fr], bfr[fc], acc[fr][fc], 0, 0, 0);
        __syncthreads();
    }
#pragma unroll
    for (int fc = 0; fc < 4; ++fc) {
        int col = n0 + wn + fc * 16 + l15;
        float bv = bias[col];
#pragma unroll
        for (int fr = 0; fr < 4; ++fr) {
#pragma unroll
            for (int r = 0; r < 4; ++r) {
                int row = m0 + wm + fr * 16 + lhi * 4 + r;
                C16[(long long)row * N + col] = f2b(acc[fr][fc][r] + bv);
            }
        }
    }
}

// ---------------- fused dual convT(1,8) tap-reduce ----------------
__global__ void dual_reduce_k(const ushort* __restrict__ YF, const ushort* __restrict__ YT,
                              const float* __restrict__ f_ctb, const float* __restrict__ t_ctb,
                              const float* __restrict__ ag, float* __restrict__ tout)
{
    int gid = blockIdx.x * blockDim.x + threadIdx.x;   // 2,097,152
    int d = gid & 63; int rest = gid >> 6;
    int f = rest & 31; rest >>= 5;
    int t = rest & 63; int b = rest >> 6;
    float v = f_ctb[d] + t_ctb[d];
    long long ybF = ((long long)(b * 64 + t)) * LF;
    long long ybT = ((long long)(b * 32 + f)) * LT;
#pragma unroll
    for (int tap = 0; tap < 8; ++tap) {
        int lf = f + tap - 7;
        if (lf >= 0 && lf < LF) v += b2f(YF[(ybF + lf) * 512 + tap * 64 + d]);
        int lt = t + tap - 7;
        if (lt >= 0 && lt < LT) v += b2f(YT[(ybT + lt) * 512 + tap * 64 + d]);
    }
    long long oi = (((long long)(b * 64 + d)) * 64 + t) * 32 + f;
    tout[oi] = v + ag[oi];
}

// ---------------- compress: f32 NCHW in -> bf16 NCHW out (implicit MFMA GEMM) ----------
__global__ __launch_bounds__(256) void mfma_nchw_o16_k(
    const float* __restrict__ X, const ushort* __restrict__ WT,
    const float* __restrict__ bias, ushort* __restrict__ Y16,
    int P, int N, int K)
{
    constexpr int FC = 2;   // BN = 64
    __shared__ ushort As[128][40];
    int p0 = blockIdx.x * 128;
    int n0 = 0;
    int b  = blockIdx.z;
    int tid = threadIdx.x, wave = tid >> 6, lane = tid & 63;
    int l15 = lane & 15, lhi = lane >> 4;
    int wm = (wave & 1) * 64, wn = (wave >> 1) * 32;
    f32x4 acc[4][FC] = {};
    const float* Xb = X + (long long)b * K * P;
    int kk_s = tid >> 3, pq_s = tid & 7;

    for (int k0 = 0; k0 < K; k0 += 32) {
        const float* xr = Xb + (long long)(k0 + kk_s) * P + p0;
#pragma unroll
        for (int j = 0; j < 4; ++j) {
            float4 v = *(const float4*)(xr + j * 32 + pq_s * 4);
            int pp = j * 32 + pq_s * 4;
            As[pp][kk_s]     = f2b(v.x);
            As[pp + 1][kk_s] = f2b(v.y);
            As[pp + 2][kk_s] = f2b(v.z);
            As[pp + 3][kk_s] = f2b(v.w);
        }
        __syncthreads();
        bf16x8 af[4], bfr[FC];
#pragma unroll
        for (int fr = 0; fr < 4; ++fr)
            af[fr] = *(const bf16x8*)&As[wm + fr * 16 + l15][lhi * 8];
#pragma unroll
        for (int fc = 0; fc < FC; ++fc)
            bfr[fc] = *(const bf16x8*)(WT + (long long)(n0 + wn + fc * 16 + l15) * K + k0 + lhi * 8);
#pragma unroll
        for (int fr = 0; fr < 4; ++fr)
#pragma unroll
            for (int fc = 0; fc < FC; ++fc)
                acc[fr][fc] = __builtin_amdgcn_mfma_f32_16x16x32_bf16(af[fr], bfr[fc], acc[fr][fc], 0, 0, 0);
        __syncthreads();
    }
#pragma unroll
    for (int fc = 0; fc < FC; ++fc) {
        int n = n0 + wn + fc * 16 + l15;
        float bv = bias[n];
        ushort* yr = Y16 + ((long long)(b * N + n)) * P + p0 + wm + lhi * 4;
#pragma unroll
        for (int fr = 0; fr < 4; ++fr) {
            uint2 o;
            o.x = cvtpk_bf16(acc[fr][fc][0] + bv, acc[fr][fc][1] + bv);
            o.y = cvtpk_bf16(acc[fr][fc][2] + bv, acc[fr][fc][3] + bv);
            *(uint2*)(yr + fr * 16) = o;
        }
    }
}

// ---------------- final: bf16 NCHW in -> f32 out ----------------
__global__ __launch_bounds__(256) void mfma_nchw16_k(
    const ushort* __restrict__ X, const ushort* __restrict__ WT,
    const float* __restrict__ bias, float* __restrict__ Y,
    int P, int N, int K)
{
    constexpr int BN = 128, FC = 4;
    __shared__ ushort As[128][40];
    int p0 = blockIdx.x * 128;
    int n0 = blockIdx.y * BN;
    int b  = blockIdx.z;
    int tid = threadIdx.x, wave = tid >> 6, lane = tid & 63;
    int l15 = lane & 15, lhi = lane >> 4;
    int wm = (wave & 1) * 64, wn = (wave >> 1) * (BN / 2);
    f32x4 acc[4][FC] = {};
    const ushort* Xb = X + (long long)b * K * P;
    int kk_s = tid >> 3, pq_s = tid & 7;

    for (int k0 = 0; k0 < K; k0 += 32) {
        const ushort* xr = Xb + (long long)(k0 + kk_s) * P + p0 + pq_s * 16;
#pragma unroll
        for (int j = 0; j < 2; ++j) {
            uint4 v = *(const uint4*)(xr + j * 8);
            const ushort* e = (const ushort*)&v;
            int pp = pq_s * 16 + j * 8;
#pragma unroll
            for (int t = 0; t < 8; ++t) As[pp + t][kk_s] = e[t];
        }
        __syncthreads();
        bf16x8 af[4], bfr[FC];
#pragma unroll
        for (int fr = 0; fr < 4; ++fr)
            af[fr] = *(const bf16x8*)&As[wm + fr * 16 + l15][lhi * 8];
#pragma unroll
        for (int fc = 0; fc < FC; ++fc)
            bfr[fc] = *(const bf16x8*)(WT + (long long)(n0 + wn + fc * 16 + l15) * K + k0 + lhi * 8);
#pragma unroll
        for (int fr = 0; fr < 4; ++fr)
#pragma unroll
            for (int fc = 0; fc < FC; ++fc)
                acc[fr][fc] = __builtin_amdgcn_mfma_f32_16x16x32_bf16(af[fr], bfr[fc], acc[fr][fc], 0, 0, 0);
        __syncthreads();
    }
#pragma unroll
    for (int fc = 0; fc < FC; ++fc) {
        int n = n0 + wn + fc * 16 + l15;
        float bv = bias[n];
        float* yr = Y + ((long long)(b * N + n)) * P + p0 + wm + lhi * 4;
#pragma unroll
        for (int fr = 0; fr < 4; ++fr) {
            float4 o;
            o.x = acc[fr][fc][0] + bv;
            o.y = acc[fr][fc][1] + bv;
            o.z = acc[fr][fc][2] + bv;
            o.w = acc[fr][fc][3] + bv;
            *(float4*)(yr + fr * 16) = o;
        }
    }
}

// ---------------- 3x3 s2 p1 conv + ReLU; bf16 NCHW input; OUT16 selects bf16 out -------
template<int OUT16>
__global__ __launch_bounds__(256) void down_mfma_k(
    const ushort* __restrict__ in, const ushort* __restrict__ WT9,
    const float* __restrict__ bias, float* __restrict__ out,
    ushort* __restrict__ o16, int Hi, int Wi)
{
    __shared__ ushort Is[289][64];
    int Ho = Hi >> 1, Wo = Wi >> 1;
    int ntx = Wo >> 3, nty = Ho >> 3;
    int tx = blockIdx.x % ntx; int rest = blockIdx.x / ntx;
    int ty = rest % nty; int b = rest / nty;
    int oy0 = ty * 8, ox0 = tx * 8;
    int iy0 = oy0 * 2 - 1, ix0 = ox0 * 2 - 1;
    int tid = threadIdx.x, wave = tid >> 6, lane = tid & 63;
    int l15 = lane & 15, lhi = lane >> 4;
    int wm = (wave & 1) * 32, wn = (wave >> 1) * 32;

    const ushort* ib = in + (long long)b * 64 * Hi * Wi;
    for (int i = tid; i < 289 * 64; i += 256) {
        int c = i / 289; int sp = i - c * 289;
        int r = sp / 17; int s = sp - r * 17;
        int iy = iy0 + r, ix = ix0 + s;
        ushort v = 0;
        if (iy >= 0 && iy < Hi && ix >= 0 && ix < Wi)
            v = ib[(long long)c * Hi * Wi + (long long)iy * Wi + ix];
        Is[sp][c ^ ((sp & 7) << 3)] = v;
    }
    __syncthreads();

    f32x4 acc[2][2] = {};
#pragma unroll
    for (int tap = 0; tap < 9; ++tap) {
        int kh = tap / 3, kw = tap - kh * 3;
#pragma unroll
        for (int half = 0; half < 2; ++half) {
            int c0 = half * 32 + lhi * 8;
            bf16x8 af[2], bw[2];
#pragma unroll
            for (int fr = 0; fr < 2; ++fr) {
                int p = wm + fr * 16 + l15;
                int sp = (2 * (p >> 3) + kh) * 17 + 2 * (p & 7) + kw;
                af[fr] = *(const bf16x8*)&Is[sp][c0 ^ ((sp & 7) << 3)];
            }
#pragma unroll
            for (int fc = 0; fc < 2; ++fc) {
                int d = wn + fc * 16 + l15;
                bw[fc] = *(const bf16x8*)(WT9 + (tap * 64 + d) * 64 + c0);
            }
#pragma unroll
            for (int fr = 0; fr < 2; ++fr)
#pragma unroll
                for (int fc = 0; fc < 2; ++fc)
                    acc[fr][fc] = __builtin_amdgcn_mfma_f32_16x16x32_bf16(af[fr], bw[fc], acc[fr][fc], 0, 0, 0);
        }
    }
#pragma unroll
    for (int fc = 0; fc < 2; ++fc) {
        int d = wn + fc * 16 + l15;
        float bv = bias[d];
        long long obase = ((long long)(b * 64 + d)) * Ho * Wo;
#pragma unroll
        for (int fr = 0; fr < 2; ++fr) {
#pragma unroll
            for (int r = 0; r < 4; ++r) {
                int p = wm + fr * 16 + lhi * 4 + r;
                int py = p >> 3, px = p & 7;
                long long oi = obase + (long long)(oy0 + py) * Wo + ox0 + px;
                float v = fmaxf(acc[fr][fc][r] + bv, 0.f);
                if (OUT16) o16[oi] = f2b(v);
                else       out[oi] = v;
            }
        }
    }
}

// ---------------- convT k=2 s=2 as MFMA; bf16 resid; OUT16 selects bf16 out ------------
template<int OUT16>
__global__ __launch_bounds__(256) void up_mfma_k(
    const float* __restrict__ in, const ushort* __restrict__ WT,
    const float* __restrict__ bias, const ushort* __restrict__ resid16,
    float* __restrict__ out, ushort* __restrict__ o16, int P, int wsh)
{
    __shared__ ushort As[128][72];
    int p0 = blockIdx.x * 128;
    int n0 = blockIdx.y * 128;
    int b  = blockIdx.z;
    int tid = threadIdx.x, wave = tid >> 6, lane = tid & 63;
    int l15 = lane & 15, lhi = lane >> 4;
    int wm = (wave & 1) * 64, wn = (wave >> 1) * 64;
    int Wi = 1 << wsh;
    int Ho = ((P >> wsh) << 1), Wo = Wi << 1;

    int kk_s = tid >> 3, pq_s = tid & 7;
#pragma unroll
    for (int h = 0; h < 2; ++h) {
        int k = h * 32 + kk_s;
        const float* xr = in + ((long long)(b * 64 + k)) * P + p0 + pq_s * 16;
#pragma unroll
        for (int j = 0; j < 4; ++j) {
            float4 v = *(const float4*)(xr + j * 4);
            int pp = pq_s * 16 + j * 4;
            As[pp][k]     = f2b(v.x);
            As[pp + 1][k] = f2b(v.y);
            As[pp + 2][k] = f2b(v.z);
            As[pp + 3][k] = f2b(v.w);
        }
    }
    __syncthreads();

    f32x4 acc[4][4] = {};
#pragma unroll
    for (int c = 0; c < 2; ++c) {
        bf16x8 af[4], bfr[4];
#pragma unroll
        for (int fr = 0; fr < 4; ++fr)
            af[fr] = *(const bf16x8*)&As[wm + fr * 16 + l15][c * 32 + lhi * 8];
#pragma unroll
        for (int fc = 0; fc < 4; ++fc)
            bfr[fc] = *(const bf16x8*)(WT + (long long)(n0 + wn + fc * 16 + l15) * 64 + c * 32 + lhi * 8);
#pragma unroll
        for (int fr = 0; fr < 4; ++fr)
#pragma unroll
            for (int fc = 0; fc < 4; ++fc)
                acc[fr][fc] = __builtin_amdgcn_mfma_f32_16x16x32_bf16(af[fr], bfr[fc], acc[fr][fc], 0, 0, 0);
    }

#pragma unroll
    for (int fc = 0; fc < 4; ++fc) {
        int n = n0 + wn + fc * 16 + l15;
        int parity = n >> 6, d = n & 63;
        int py = parity >> 1, px = parity & 1;
        float bv = bias[d];
        const long long obase = ((long long)(b * 64 + d)) * Ho * Wo;
#pragma unroll
        for (int fr = 0; fr < 4; ++fr) {
#pragma unroll
            for (int r = 0; r < 4; ++r) {
                int p = p0 + wm + fr * 16 + lhi * 4 + r;
                int iy = p >> wsh, ix = p & (Wi - 1);
                long long oi = obase + (long long)(2 * iy + py) * Wo + 2 * ix + px;
                float v = acc[fr][fc][r] + bv + b2f(resid16[oi]);
                if (OUT16) o16[oi] = f2b(v);
                else       out[oi] = v;
            }
        }
    }
}

// ---------------- qkv projection -> bf16 [b][p][192] ----------------
__global__ __launch_bounds__(256) void mfma_qkv_k(
    const float* __restrict__ X, const ushort* __restrict__ WT,
    const float* __restrict__ bias, ushort* __restrict__ C16)
{
    __shared__ ushort As[128][72];
    int p0 = blockIdx.x * 128;
    int b  = blockIdx.z;
    int tid = threadIdx.x, wave = tid >> 6, lane = tid & 63;
    int l15 = lane & 15, lhi = lane >> 4;
    int wm = (wave & 1) * 64, wn = (wave >> 1) * 96;

    int kk_s = tid >> 3, pq_s = tid & 7;
#pragma unroll
    for (int h = 0; h < 2; ++h) {
        int k = h * 32 + kk_s;
        const float* xr = X + ((long long)(b * 64 + k)) * P4 + p0 + pq_s * 16;
#pragma unroll
        for (int j = 0; j < 4; ++j) {
            float4 v = *(const float4*)(xr + j * 4);
            int pp = pq_s * 16 + j * 4;
            As[pp][k]     = f2b(v.x);
            As[pp + 1][k] = f2b(v.y);
            As[pp + 2][k] = f2b(v.z);
            As[pp + 3][k] = f2b(v.w);
        }
    }
    __syncthreads();

    f32x4 acc[4][6] = {};
#pragma unroll
    for (int c = 0; c < 2; ++c) {
        bf16x8 af[4], bfr[6];
#pragma unroll
        for (int fr = 0; fr < 4; ++fr)
            af[fr] = *(const bf16x8*)&As[wm + fr * 16 + l15][c * 32 + lhi * 8];
#pragma unroll
        for (int fc = 0; fc < 6; ++fc)
            bfr[fc] = *(const bf16x8*)(WT + (long long)(wn + fc * 16 + l15) * 64 + c * 32 + lhi * 8);
#pragma unroll
        for (int fr = 0; fr < 4; ++fr)
#pragma unroll
            for (int fc = 0; fc < 6; ++fc)
                acc[fr][fc] = __builtin_amdgcn_mfma_f32_16x16x32_bf16(af[fr], bfr[fc], acc[fr][fc], 0, 0, 0);
    }
#pragma unroll
    for (int fc = 0; fc < 6; ++fc) {
        int n = wn + fc * 16 + l15;
        float bv = bias[n];
#pragma unroll
        for (int fr = 0; fr < 4; ++fr)
#pragma unroll
            for (int r = 0; r < 4; ++r) {
                int p = p0 + wm + fr * 16 + lhi * 4 + r;
                C16[((long long)(b * P4 + p)) * 192 + n] = f2b(acc[fr][fc][r] + bv);
            }
    }
}

// ---------------- attention out-proj ----------------
__global__ __launch_bounds__(256) void mfma_attnout_k(
    const float* __restrict__ A, const ushort* __restrict__ owT,
    const float* __restrict__ ob, const float* __restrict__ resid,
    float* __restrict__ dp)
{
    __shared__ ushort As[128][72];
    int p0 = blockIdx.x * 128;
    int b  = blockIdx.z;
    int tid = threadIdx.x, wave = tid >> 6, lane = tid & 63;
    int l15 = lane & 15, lhi = lane >> 4;
    int wm = (wave & 1) * 64, wn = (wave >> 1) * 32;

    int rs = tid >> 2, qs = tid & 3;
#pragma unroll
    for (int h = 0; h < 2; ++h) {
        int row = h * 64 + rs;
        const float* ar = A + ((long long)(b * P4 + p0 + row)) * 64 + qs * 16;
#pragma unroll
        for (int j = 0; j < 4; ++j) {
            float4 v = *(const float4*)(ar + j * 4);
            int c = qs * 16 + j * 4;
            *(unsigned*)&As[row][c]     = cvtpk_bf16(v.x, v.y);
            *(unsigned*)&As[row][c + 2] = cvtpk_bf16(v.z, v.w);
        }
    }
    __syncthreads();

    f32x4 acc[4][2] = {};
#pragma unroll
    for (int c = 0; c < 2; ++c) {
        bf16x8 af[4], bfr[2];
#pragma unroll
        for (int fr = 0; fr < 4; ++fr)
            af[fr] = *(const bf16x8*)&As[wm + fr * 16 + l15][c * 32 + lhi * 8];
#pragma unroll
        for (int fc = 0; fc < 2; ++fc)
            bfr[fc] = *(const bf16x8*)(owT + (long long)(wn + fc * 16 + l15) * 64 + c * 32 + lhi * 8);
#pragma unroll
        for (int fr = 0; fr < 4; ++fr)
#pragma unroll
            for (int fc = 0; fc < 2; ++fc)
                acc[fr][fc] = __builtin_amdgcn_mfma_f32_16x16x32_bf16(af[fr], bfr[fc], acc[fr][fc], 0, 0, 0);
    }
#pragma unroll
    for (int fc = 0; fc < 2; ++fc) {
        int n = wn + fc * 16 + l15;
        float bv = ob[n];
        long long base = ((long long)(b * 64 + n)) * P4;
#pragma unroll
        for (int fr = 0; fr < 4; ++fr) {
            int p = p0 + wm + fr * 16 + lhi * 4;
            float4 rv = *(const float4*)(resid + base + p);
            float4 o;
            o.x = acc[fr][fc][0] + bv + rv.x;
            o.y = acc[fr][fc][1] + bv + rv.y;
            o.z = acc[fr][fc][2] + bv + rv.z;
            o.w = acc[fr][fc][3] + bv + rv.w;
            *(float4*)(dp + base + p) = o;
        }
    }
}

// ---------------- MFMA flash attention (dh=16, 4 heads), bf16 qkv input ----------------
__global__ __launch_bounds__(256) void attn_mfma_k(const ushort* __restrict__ qkv,
                                                   float* __restrict__ out)
{
    __shared__ ushort Qs[128][40];
    __shared__ ushort Ks[64][40];
    __shared__ ushort VsT[16][72];
    __shared__ ushort Ps[128][72];
    int qt = blockIdx.x, h = blockIdx.y, b = blockIdx.z;
    int tid = threadIdx.x, wave = tid >> 6, lane = tid & 63;
    int l15 = lane & 15, lhi = lane >> 4;
    int q0 = wave * 32;

    for (int i = tid; i < 1024; i += 256) {
        int row = i >> 3, c = i & 7;
        *(unsigned*)&Qs[row][16 + c * 2] = 0u;
    }
    for (int i = tid; i < 512; i += 256) {
        int row = i >> 3, c = i & 7;
        *(unsigned*)&Ks[row][16 + c * 2] = 0u;
    }
    {
        const ushort* qp = qkv + ((long long)(b * P4 + qt * 128)) * 192 + h * 16;
        for (int i = tid; i < 2048; i += 256) {
            int row = i >> 4, d = i & 15;
            Qs[row][d] = f2b(b2f(qp[row * 192 + d]) * 0.25f);
        }
    }
    __syncthreads();

    float mmax[2] = {-1e30f, -1e30f};
    float lsum[2] = {0.f, 0.f};
    f32x4 oacc[2] = {};

    for (int k0 = 0; k0 < P4; k0 += 64) {
        const ushort* kp = qkv + ((long long)(b * P4 + k0)) * 192 + 64 + h * 16;
        for (int i = tid; i < 1024; i += 256) {
            int key = i >> 4, d = i & 15;
            Ks[key][d]  = kp[key * 192 + d];
            VsT[d][key] = kp[key * 192 + 64 + d];
        }
        __syncthreads();

        bf16x8 bq[2];
        bq[0] = *(const bf16x8*)&Qs[q0 + l15][lhi * 8];
        bq[1] = *(const bf16x8*)&Qs[q0 + 16 + l15][lhi * 8];
        f32x4 s[4][2];
#pragma unroll
        for (int fr = 0; fr < 4; ++fr) {
            bf16x8 ak = *(const bf16x8*)&Ks[fr * 16 + l15][lhi * 8];
            f32x4 z = {};
            s[fr][0] = __builtin_amdgcn_mfma_f32_16x16x32_bf16(ak, bq[0], z, 0, 0, 0);
            s[fr][1] = __builtin_amdgcn_mfma_f32_16x16x32_bf16(ak, bq[1], z, 0, 0, 0);
        }
#pragma unroll
        for (int fc = 0; fc < 2; ++fc) {
            float m = s[0][fc][0];
#pragma unroll
            for (int fr = 0; fr < 4; ++fr)
#pragma unroll
                for (int r = 0; r < 4; ++r) m = fmaxf(m, s[fr][fc][r]);
            m = fmaxf(m, __shfl_xor(m, 16));
            m = fmaxf(m, __shfl_xor(m, 32));
            float nm = fmaxf(mmax[fc], m);
            float corr = __expf(mmax[fc] - nm);
            mmax[fc] = nm;
            float ps = 0.f;
#pragma unroll
            for (int fr = 0; fr < 4; ++fr)
#pragma unroll
                for (int r = 0; r < 4; ++r) {
                    float p = __expf(s[fr][fc][r] - nm);
                    s[fr][fc][r] = p;
                    ps += p;
                }
            lsum[fc] = lsum[fc] * corr + ps;
#pragma unroll
            for (int r = 0; r < 4; ++r) oacc[fc][r] *= corr;
        }
#pragma unroll
        for (int fc = 0; fc < 2; ++fc)
#pragma unroll
            for (int fr = 0; fr < 4; ++fr) {
                uint2 pk;
                pk.x = cvtpk_bf16(s[fr][fc][0], s[fr][fc][1]);
                pk.y = cvtpk_bf16(s[fr][fc][2], s[fr][fc][3]);
                *(uint2*)&Ps[q0 + fc * 16 + l15][fr * 16 + lhi * 4] = pk;
            }
#pragma unroll
        for (int ks = 0; ks < 2; ++ks) {
            bf16x8 av = *(const bf16x8*)&VsT[l15][ks * 32 + lhi * 8];
#pragma unroll
            for (int fc = 0; fc < 2; ++fc) {
                bf16x8 bp = *(const bf16x8*)&Ps[q0 + fc * 16 + l15][ks * 32 + lhi * 8];
                oacc[fc] = __builtin_amdgcn_mfma_f32_16x16x32_bf16(av, bp, oacc[fc], 0, 0, 0);
            }
        }
        __syncthreads();
    }
#pragma unroll
    for (int fc = 0; fc < 2; ++fc) {
        float L = lsum[fc];
        L += __shfl_xor(L, 16);
        L += __shfl_xor(L, 32);
        float inv = 1.f / L;
        int q = qt * 128 + q0 + fc * 16 + l15;
        float* op = out + ((long long)(b * P4 + q)) * 64 + h * 16 + lhi * 4;
#pragma unroll
        for (int r = 0; r < 4; ++r) op[r] = oacc[fc][r] * inv;
    }
}

// ---------------- host launch ----------------
extern "C" void kernel_launch(void* const* d_in, const int* in_sizes, int n_in,
                              void* d_out, int out_size, void* d_ws, size_t ws_size,
                              hipStream_t stream)
{
    const float* A_in  = (const float*)d_in[0];
    const float* cw    = (const float*)d_in[1];
    const float* cb    = (const float*)d_in[2];
    const float* dw0   = (const float*)d_in[3];
    const float* db0   = (const float*)d_in[4];
    const float* dw1   = (const float*)d_in[5];
    const float* db1   = (const float*)d_in[6];
    const float* f_Wx  = (const float*)d_in[7];
    const float* f_bf  = (const float*)d_in[8];
    const float* f_br  = (const float*)d_in[9];
    const float* f_Whw = (const float*)d_in[10];
    const float* f_pw  = (const float*)d_in[11];
    const float* f_pb  = (const float*)d_in[12];
    const float* f_ctw = (const float*)d_in[13];
    const float* f_ctb = (const float*)d_in[14];
    const float* t_Wx  = (const float*)d_in[15];
    const float* t_bf  = (const float*)d_in[16];
    const float* t_br  = (const float*)d_in[17];
    const float* t_Whw = (const float*)d_in[18];
    const float* t_pw  = (const float*)d_in[19];
    const float* t_pb  = (const float*)d_in[20];
    const float* t_ctw = (const float*)d_in[21];
    const float* t_ctb = (const float*)d_in[22];
    const float* qkv_w = (const float*)d_in[23];
    const float* qkv_b = (const float*)d_in[24];
    const float* ow    = (const float*)d_in[25];
    const float* ob    = (const float*)d_in[26];
    const float* upw0  = (const float*)d_in[27];
    const float* upb0  = (const float*)d_in[28];
    const float* upw1  = (const float*)d_in[29];
    const float* upb1  = (const float*)d_in[30];
    const float* fw    = (const float*)d_in[31];
    const float* fb    = (const float*)d_in[32];

    float* ws  = (float*)d_ws;
    float* out = (float*)d_out;

    // ---- workspace layout (f32 units) ----
    float* ag    = ws + 0;          // 1,048,576 f32
    float* x016f = ws + 1048576;    // 8,388,608 (16.7M bf16: compress out)
    float* x116f = ws + 9437184;    // 2,097,152 (4.2M bf16: down0 out)
    float* uFf   = ws + 11534336;   // 3,276,800 (bf16)   [later YF16, then qkv16]
    float* uTf   = ws + 14811136;   // 3,735,552 (bf16)   [later YT16, then attnO]
    float* GxtF  = ws + 18546688;   // 3,276,800 f32      [later y1]
    float* GxhF  = ws + 21823488;   // 3,276,800 f32
    float* GxtT  = ws + 25100288;   // 3,735,552 f32      [later y016]
    float* GxhT  = ws + 28835840;   // 3,735,552 f32
    float* GfFf  = ws + 32571392;   // 1,638,400 (bf16)
    float* GrFf  = ws + 34209792;   // 1,638,400
    float* GfTf  = ws + 35848192;   // 1,867,776
    float* GrTf  = ws + 37715968;   // 1,867,776
    float* hFf   = ws + 39583744;   // 1,638,400 (bf16)   [later tout]
    float* hTf   = ws + 41222144;   // 1,867,776 (bf16)   [later dp]
    // overlays:
    float* YF16f = uFf;             // gemmW out (bf16), after gates
    float* YT16f = uTf;
    float* y1    = GxtF;            // 4,194,304 f32 (spans GxtF + part GxhF)
    float* y016f = GxtT;            // 8,388,608 (spans GxtT/GxhT/part GfF)
    float* tout  = hFf;             // 1,048,576 f32 (hF dead after gemmW)
    float* dp    = hTf;             // 1,048,576 f32
    float* qkvbf = uFf;             // 1,572,864 (bf16 qkv) after dual_reduce
    float* attnO = uTf;             // 1,048,576 f32 after dual_reduce
    // weights (live whole time):
    float* pwFf  = ws + 43089920;   // 65,536
    float* pwTf  = ws + 43155456;   // 65,536
    float* w3Ff  = ws + 43220992;   // 65,536
    float* w3Tf  = ws + 43286528;   // 65,536
    float* b3Ff  = ws + 43352064;   // 512
    float* b3Tf  = ws + 43352576;   // 512
    float* wctFf = ws + 43353088;   // 131,072
    float* wctTf = ws + 43484160;   // 131,072
    float* wcaFf = ws + 43615232;   // 262,144
    float* wcaTf = ws + 43877376;   // 262,144
    float* cw16f = ws + 44139520;   // 8,192
    float* fw16f = ws + 44147712;   // 8,192
    float* wup0f = ws + 44155904;   // 8,192
    float* wup1f = ws + 44164096;   // 8,192
    float* qkvwf = ws + 44172288;   // 6,144
    float* owtf  = ws + 44178432;   // 2,048
    float* wdw0f = ws + 44180480;   // 18,432
    float* wdw1f = ws + 44198912;   // 18,432 -> total 44,217,344 f32 (~177 MB)

    ushort* x016   = (ushort*)x016f;
    ushort* x116   = (ushort*)x116f;
    ushort* uF     = (ushort*)uFf;
    ushort* uT     = (ushort*)uTf;
    ushort* GfF    = (ushort*)GfFf;
    ushort* GrF    = (ushort*)GrFf;
    ushort* GfT    = (ushort*)GfTf;
    ushort* GrT    = (ushort*)GrTf;
    ushort* hF     = (ushort*)hFf;
    ushort* hT     = (ushort*)hTf;
    ushort* YF16   = (ushort*)YF16f;
    ushort* YT16   = (ushort*)YT16f;
    ushort* y016   = (ushort*)y016f;
    ushort* qkv16  = (ushort*)qkvbf;
    ushort* pwF16  = (ushort*)pwFf;
    ushort* pwT16  = (ushort*)pwTf;
    ushort* W3F    = (ushort*)w3Ff;
    ushort* W3T_   = (ushort*)w3Tf;
    ushort* WctF   = (ushort*)wctFf;
    ushort* WctT_  = (ushort*)wctTf;
    ushort* WcatF  = (ushort*)wcaFf;
    ushort* WcatTm = (ushort*)wcaTf;
    ushort* cw16   = (ushort*)cw16f;
    ushort* fw16   = (ushort*)fw16f;
    ushort* WupT0  = (ushort*)wup0f;
    ushort* WupT1  = (ushort*)wup1f;
    ushort* qkvwT  = (ushort*)qkvwf;
    ushort* owT    = (ushort*)owtf;
    ushort* WT9d0  = (ushort*)wdw0f;
    ushort* WT9d1  = (ushort*)wdw1f;

    dim3 blk(256);

    // ---- weight packs + W3/bias3 precompute ----
    pack_all_k<<<dim3(7776), blk, 0, stream>>>(
        cw, fw, upw0, upw1, qkv_w, ow, dw0, dw1, f_pw, t_pw, f_ctw, t_ctw,
        f_Wx, f_Whw, t_Wx, t_Whw,
        cw16, fw16, WupT0, WupT1, qkvwT, owT, WT9d0, WT9d1,
        pwF16, pwT16, WctF, WctT_, WcatF, WcatTm);
    w3_gemm_k<<<dim3(4, 2, 2), blk, 0, stream>>>(pwF16, WctF, pwT16, WctT_, W3F, W3T_);
    bias3_red_k<<<dim3(512, 2), blk, 0, stream>>>(f_pb, f_ctw, t_pb, t_ctw, b3Ff, b3Tf);

    // 1. compress -> bf16 x0 (in ws; d_out now written only by final conv)
    mfma_nchw_o16_k<<<dim3(256, 1, 8), blk, 0, stream>>>(A_in, cw16, cb, x016, 32768, 64, 256);

    // 2-3. downsample (bf16 in; down0 -> bf16 x1, down1 -> f32 ag)
    down_mfma_k<1><<<dim3(1024), blk, 0, stream>>>(x016, WT9d0, db0, nullptr, x116, TT, FF);
    down_mfma_k<0><<<dim3(256), blk, 0, stream>>>(x116, WT9d1, db1, ag, nullptr, T2, F2);

    // ---- both pathways, batched ----
    unfold_both_k<<<dim3(54784), blk, 0, stream>>>(ag, uF, uT);
    gates_fused_k<<<dim3(8, 214), blk, 0, stream>>>(uF, uT, WcatF, WcatTm,
        GxtF, GxhF, GfF, GrF, GxtT, GxhT, GfT, GrT, f_bf, f_br, t_bf, t_br);
    sru_scan_both_k<<<dim3(768), blk, 0, stream>>>(GxtF, GxhF, GfF, GrF, hF,
                                                   GxtT, GxhT, GfT, GrT, hT);
    gemmW_both_k<<<dim3(4, 214), blk, 0, stream>>>(hF, W3F, YF16, b3Ff,
                                                   hT, W3T_, YT16, b3Tf);
    dual_reduce_k<<<dim3(8192), blk, 0, stream>>>(YF16, YT16, f_ctb, t_ctb, ag, tout);

    // ---- attention ----
    mfma_qkv_k<<<dim3(16, 1, 8), blk, 0, stream>>>(tout, qkvwT, qkv_b, qkv16);
    attn_mfma_k<<<dim3(16, NHEADS, BB), blk, 0, stream>>>(qkv16, attnO);
    mfma_attnout_k<<<dim3(16, 1, 8), blk, 0, stream>>>(attnO, owT, ob, tout, dp);

    // ---- reconstruction (bf16 residuals) ----
    up_mfma_k<0><<<dim3(16, 2, 8), blk, 0, stream>>>(dp, WupT0, upb0, x116, y1, nullptr, 2048, 5);
    up_mfma_k<1><<<dim3(64, 2, 8), blk, 0, stream>>>(y1, WupT1, upb1, x016, nullptr, y016, 8192, 6);

    // final 1x1 conv (bf16 NCHW input) -> d_out
    mfma_nchw16_k<<<dim3(256, 2, 8), blk, 0, stream>>>(y016, fw16, fb, out, 32768, 256, 64);
}